// Round 14
// baseline (135.273 us; speedup 1.0000x reference)
//
#include <hip/hip_runtime.h>
#include <hip/hip_bf16.h>
#include <stdint.h>

// Problem constants
#define NU 4000
#define NI 4000
#define RR 5
#define MM 256
#define OUTD 75
#define FDIM 128
#define KP 4096                 // padded K length (P rows)
#define KPH 2048                // packed A row bytes (KP/2)
#define HP_STRIDE 1024000       // 4000*256 elements per partial

typedef float f32x4 __attribute__((ext_vector_type(4)));
typedef int   i32x4 __attribute__((ext_vector_type(4)));
typedef short bf16x8 __attribute__((ext_vector_type(8)));

static __device__ __forceinline__ short f2b(float x) {
  __hip_bfloat16 h = __float2bfloat16(x);
  return (short)__builtin_bit_cast(unsigned short, h);
}
static __device__ __forceinline__ float b2f(short x) {
  unsigned int u = ((unsigned int)(unsigned short)x) << 16;
  return __builtin_bit_cast(float, u);
}
static __device__ __forceinline__ bf16x8 cvt8(f32x4 a, f32x4 b) {
  bf16x8 r;
  r[0] = f2b(a[0]); r[1] = f2b(a[1]); r[2] = f2b(a[2]); r[3] = f2b(a[3]);
  r[4] = f2b(b[0]); r[5] = f2b(b[1]); r[6] = f2b(b[2]); r[7] = f2b(b[3]);
  return r;
}

// ---------------------------------------------------------------------------
// K1: adj -> nibble-packed int8 (both layouts) + degree counts. (proven R13)
// ---------------------------------------------------------------------------
__global__ __launch_bounds__(256) void k_trans(const int* __restrict__ adj,
                                               uint8_t* __restrict__ a8p,
                                               uint8_t* __restrict__ a8tp,
                                               int* __restrict__ Nu,
                                               int* __restrict__ Nv) {
  __shared__ int8_t lp[64][68];   // direct:     lp[u_local][i_local]
  __shared__ int8_t lt[64][68];   // transposed: lt[i_local][u_local]
  __shared__ int rowc[64];
  __shared__ int colp[4][64];
  const int i0 = blockIdx.x * 64;
  const int u0 = blockIdx.y * 64;
  const int t = threadIdx.x;
  const int w = t >> 6, lane = t & 63;
  int mycol = 0;
  for (int rep = 0; rep < 16; rep++) {
    const int r = rep * 4 + w;
    const int u = u0 + r, i = i0 + lane;
    int a = (u < NU && i < NI) ? adj[(size_t)u * NI + i] : 0;
    const int nz = (a > 0) ? 1 : 0;
    unsigned long long bal = __ballot(nz);
    if (lane == 0) rowc[r] = (int)__popcll(bal);
    mycol += nz;
    lp[r][lane] = (int8_t)a;
    lt[lane][r] = (int8_t)a;
  }
  colp[w][lane] = mycol;
  __syncthreads();
  // phase 2: thread -> (row r = t>>2, 16-col chunk c = t&3); pack 16 vals -> 8B
  {
    const int r = t >> 2, c = t & 3;
    const uint32_t* xp = (const uint32_t*)(&lp[r][c * 16]);
    const uint32_t* xt = (const uint32_t*)(&lt[r][c * 16]);
    uint32_t t0, t1, t2, t3, w0, w1;
    t0 = xp[0] | (xp[0] >> 4); t1 = xp[1] | (xp[1] >> 4);
    t2 = xp[2] | (xp[2] >> 4); t3 = xp[3] | (xp[3] >> 4);
    w0 = __builtin_amdgcn_perm(t1, t0, 0x06040200u);
    w1 = __builtin_amdgcn_perm(t3, t2, 0x06040200u);
    *(uint2*)(a8p + (size_t)(u0 + r) * KPH + (i0 >> 1) + c * 8) = make_uint2(w0, w1);
    t0 = xt[0] | (xt[0] >> 4); t1 = xt[1] | (xt[1] >> 4);
    t2 = xt[2] | (xt[2] >> 4); t3 = xt[3] | (xt[3] >> 4);
    w0 = __builtin_amdgcn_perm(t1, t0, 0x06040200u);
    w1 = __builtin_amdgcn_perm(t3, t2, 0x06040200u);
    *(uint2*)(a8tp + (size_t)(i0 + r) * KPH + (u0 >> 1) + c * 8) = make_uint2(w0, w1);
  }
  if (t < 64) {
    const int cc = colp[0][t] + colp[1][t] + colp[2][t] + colp[3][t];
    if (i0 + t < NI && cc) atomicAdd(&Nv[i0 + t], cc);
    if (u0 + t < NU && rowc[t]) atomicAdd(&Nu[u0 + t], rowc[t]);
  }
}

// ---------------------------------------------------------------------------
// K2: P build (int8, x256 scale), vectorized, perm folded into pack (R13);
//  block 1280 converts stage-2 weights to bf16 (folded k_wcvt, one launch less).
// ---------------------------------------------------------------------------
__global__ __launch_bounds__(256) void k_pbuild(const float* __restrict__ msgW,
                                                const int* __restrict__ Nu,
                                                const int* __restrict__ Nv,
                                                int8_t* __restrict__ Pu,
                                                int8_t* __restrict__ Pv,
                                                const float* __restrict__ dW,
                                                const float* __restrict__ uW1,
                                                const float* __restrict__ vW1,
                                                const float* __restrict__ uW2,
                                                const float* __restrict__ vW2,
                                                __hip_bfloat16* __restrict__ dWb,
                                                __hip_bfloat16* __restrict__ W1b,
                                                __hip_bfloat16* __restrict__ W2b) {
  const int b = blockIdx.x;                 // 0..1279: r*256+m; 1280: weights
  if (b == 1280) {
    const int tid = threadIdx.x;
    for (int idx = tid; idx < 80 * 256; idx += 256) {
      const int oc = idx >> 8, k = idx & 255;
      dWb[idx] = __float2bfloat16(oc < 75 ? dW[oc * 256 + k] : 0.f);
    }
    for (int idx = tid; idx < 2 * 64 * 128; idx += 256) {
      const int s = idx >> 13, r = idx & 8191;
      W1b[idx] = __float2bfloat16(s ? vW1[r] : uW1[r]);
    }
    for (int idx = tid; idx < 2 * 80 * 64; idx += 256) {
      const int s = idx / 5120, r = idx % 5120;
      const int oc = r >> 6, k = r & 63;
      const float* W2 = s ? vW2 : uW2;
      W2b[idx] = __float2bfloat16(oc < 75 ? W2[oc * 64 + k] : 0.f);
    }
    return;
  }
  const float* src = msgW + (size_t)b * (NU + NI);
#pragma unroll
  for (int it = 0; it < 2; ++it) {
    const int base = (threadIdx.x + it * 256) * 8;     // 0..4088, 8-aligned
    uint32_t lou = 0, hiu = 0, lov = 0, hiv = 0;
    if (base < NU) {                                    // NU = 8*500
      const f32x4 v0 = *(const f32x4*)(src + base);
      const f32x4 v1 = *(const f32x4*)(src + base + 4);
      const f32x4 u0 = *(const f32x4*)(src + NU + base);
      const f32x4 u1 = *(const f32x4*)(src + NU + base + 4);
      const int4 cu0 = *(const int4*)(Nu + base);
      const int4 cu1 = *(const int4*)(Nu + base + 4);
      const int4 cv0 = *(const int4*)(Nv + base);
      const int4 cv1 = *(const int4*)(Nv + base + 4);
      float qv[8], qu[8];
      const int cus[8] = {cu0.x, cu0.y, cu0.z, cu0.w, cu1.x, cu1.y, cu1.z, cu1.w};
      const int cvs[8] = {cv0.x, cv0.y, cv0.z, cv0.w, cv1.x, cv1.y, cv1.z, cv1.w};
      const float vs[8] = {v0[0], v0[1], v0[2], v0[3], v1[0], v1[1], v1[2], v1[3]};
      const float us[8] = {u0[0], u0[1], u0[2], u0[3], u1[0], u1[1], u1[2], u1[3]};
#pragma unroll
      for (int j = 0; j < 8; ++j) {
        const float su = cus[j] > 0 ? rsqrtf((float)cus[j]) * 256.0f : 0.f;
        const float sv = cvs[j] > 0 ? rsqrtf((float)cvs[j]) * 256.0f : 0.f;
        qv[j] = fminf(fmaxf(vs[j] * su, -127.f), 127.f);
        qu[j] = fminf(fmaxf(us[j] * sv, -127.f), 127.f);
      }
      uint32_t bv[8], bu[8];
#pragma unroll
      for (int j = 0; j < 8; ++j) {
        bv[j] = (uint32_t)(uint8_t)(int8_t)__float2int_rn(qv[j]);
        bu[j] = (uint32_t)(uint8_t)(int8_t)__float2int_rn(qu[j]);
      }
      lov = bv[0] | (bv[2] << 8) | (bv[4] << 16) | (bv[6] << 24);
      hiv = bv[1] | (bv[3] << 8) | (bv[5] << 16) | (bv[7] << 24);
      lou = bu[0] | (bu[2] << 8) | (bu[4] << 16) | (bu[6] << 24);
      hiu = bu[1] | (bu[3] << 8) | (bu[5] << 16) | (bu[7] << 24);
    }
    *(uint2*)(Pv + (size_t)b * KP + base) = make_uint2(lov, hiv);
    *(uint2*)(Pu + (size_t)b * KP + base) = make_uint2(lou, hiu);
  }
}

// ---------------------------------------------------------------------------
// K3: one-hot i8 MFMA GEMM — 64-col waves (density-first).
//  - 256 thr = 4 waves, block tile 256r x 64c, BK=64, 16x16x64 MFMA.
//  - Per step per wave: 80 perms -> 80 MFMA (ratio 6.5:1 in cycles, vs 2:1
//    in R10/R13): halves VALU-per-MFMA, halves A re-read redundancy (4 bn).
//  - B tile [5r][4chunk][16c][64k] = 20KB double-buffered (40KB LDS);
//    proven zero-conflict staging/read swizzle (same maps as R7/R10).
//  - 3 blocks/CU (grid 768 = 2 sides x 4 bn x 6 ks x 16 bm, launch_bounds(256,3)).
//  - R10-proven lockstep schedule: STAGE(next)+A-prefetch+compute+syncthreads.
// ---------------------------------------------------------------------------
#define GLOAD_LDS(g, s) __builtin_amdgcn_global_load_lds( \
    (const __attribute__((address_space(1))) uint32_t*)(g), \
    (__attribute__((address_space(3))) uint32_t*)(s), 16, 0, 0)

static __device__ __forceinline__ uint32_t ohp(uint32_t sel, int r) {
  // one-hot i8: result byte = 0x01 iff input byte == r+1 (inputs 0..5)
  const uint32_t TL[5] = {0x00000100u, 0x00010000u, 0x01000000u, 0u, 0u};
  const uint32_t TH[5] = {0u, 0u, 0u, 0x00000001u, 0x00000100u};
  return __builtin_amdgcn_perm(TH[r], TL[r], sel);
}

__global__ __launch_bounds__(256, 3) void k_gemm(const uint8_t* __restrict__ Au,
                                                 const uint8_t* __restrict__ Av,
                                                 const int8_t* __restrict__ Pu,
                                                 const int8_t* __restrict__ Pv,
                                                 const int* __restrict__ Nu,
                                                 const int* __restrict__ Nv,
                                                 __hip_bfloat16* __restrict__ Hp) {
  __shared__ __attribute__((aligned(16))) char Bls[2][20480];

  const int bid = blockIdx.x;
  const int side = bid & 1;
  const int bn = (bid >> 1) & 3;                   // 0..3 (64-col slices)
  const int rest = bid >> 3;                       // 0..95
  const int ks = rest % 6;
  const int bm = rest / 6;                         // 0..15 (256-row tiles)
  const uint8_t* __restrict__ A8 = side ? Av : Au;
  const int8_t* __restrict__ P  = side ? Pv : Pu;
  const int* __restrict__ cnt = side ? Nv : Nu;
  const int kbeg = (ks < 4) ? ks * 704 : 2816 + (ks - 4) * 640;
  const int nst = (ks < 4) ? 11 : 10;              // steps of 64

  const int t = threadIdx.x;
  const int w = t >> 6, l = t & 63;
  const int l15 = l & 15, l4 = l >> 4;

  // staging: 20 gload_lds per block, 5 per wave (n = w*5+i).
  // instr n: r = n>>2, chunk = n&3 (16 cols); lane l -> col chunk*16+(l>>2),
  // source 16B unit jsrc = (l&3) ^ ((l>>3)&3)   (verified zero-conflict map)
  uint32_t soff[5], ldst[5];
  {
    const uint32_t jsrc = (uint32_t)((l & 3) ^ ((l >> 3) & 3));
#pragma unroll
    for (int i = 0; i < 5; ++i) {
      const int n = w * 5 + i;
      const int r = n >> 2, chunk = n & 3;
      const int colg = bn * 64 + chunk * 16 + (l >> 2);
      soff[i] = (uint32_t)(r * 256 + colg) * KP + jsrc * 16u;
      ldst[i] = (uint32_t)(n << 10);
    }
  }
#define STAGE(bi, kk) { _Pragma("unroll") \
  for (int i_ = 0; i_ < 5; ++i_) \
    GLOAD_LDS(P + soff[i_] + (uint32_t)(kk), &Bls[bi][0] + ldst[i_]); }

  // B read base: frag(r,c) at r*4096 + c*1024 + l15*64 + ((l4^((l15>>1)&3))<<4)
  const uint32_t rbase = (uint32_t)(l15 * 64) +
                         ((uint32_t)(l4 ^ ((l15 >> 1) & 3)) << 4);

  // A: packed byte offset per 16-row frag g (rows bm*256 + w*64 + g*16 + l15)
  uint32_t paoff[4];
#pragma unroll
  for (int g = 0; g < 4; ++g)
    paoff[g] = (uint32_t)(bm * 256 + w * 64 + g * 16 + l15) * KPH + l4 * 8;

  i32x4 acc[4][4] = {};
  uint2 aC[4], aN[4];

  STAGE(0, kbeg);
#pragma unroll
  for (int g = 0; g < 4; ++g)
    aC[g] = *(const uint2*)(A8 + paoff[g] + (kbeg >> 1));
  __syncthreads();

  for (int st = 0; st < nst; ++st) {
    const int kk = kbeg + st * 64;
    if (st + 1 < nst) {
      STAGE((st & 1) ^ 1, kk + 64);
#pragma unroll
      for (int g = 0; g < 4; ++g)
        aN[g] = *(const uint2*)(A8 + paoff[g] + ((kk + 64) >> 1));
    }
    // unpack nibbles -> 4 byte-dwords per frag (k-order matches P permutation)
    uint32_t ud[4][4];
#pragma unroll
    for (int g = 0; g < 4; ++g) {
      ud[g][0] = aC[g].x & 0x0F0F0F0Fu;
      ud[g][1] = (aC[g].x >> 4) & 0x0F0F0F0Fu;
      ud[g][2] = aC[g].y & 0x0F0F0F0Fu;
      ud[g][3] = (aC[g].y >> 4) & 0x0F0F0F0Fu;
    }
    const char* lb = &Bls[st & 1][0];
#pragma unroll
    for (int r = 0; r < 5; ++r) {
      const uint4 B0 = *(const uint4*)(lb + r * 4096 + rbase);
      const uint4 B1 = *(const uint4*)(lb + r * 4096 + rbase + 1024);
      const uint4 B2 = *(const uint4*)(lb + r * 4096 + rbase + 2048);
      const uint4 B3 = *(const uint4*)(lb + r * 4096 + rbase + 3072);
#pragma unroll
      for (int g = 0; g < 4; ++g) {
        uint4 af;
        af.x = ohp(ud[g][0], r); af.y = ohp(ud[g][1], r);
        af.z = ohp(ud[g][2], r); af.w = ohp(ud[g][3], r);
        const i32x4 a4 = __builtin_bit_cast(i32x4, af);
        acc[g][0] = __builtin_amdgcn_mfma_i32_16x16x64_i8(
            a4, __builtin_bit_cast(i32x4, B0), acc[g][0], 0, 0, 0);
        acc[g][1] = __builtin_amdgcn_mfma_i32_16x16x64_i8(
            a4, __builtin_bit_cast(i32x4, B1), acc[g][1], 0, 0, 0);
        acc[g][2] = __builtin_amdgcn_mfma_i32_16x16x64_i8(
            a4, __builtin_bit_cast(i32x4, B2), acc[g][2], 0, 0, 0);
        acc[g][3] = __builtin_amdgcn_mfma_i32_16x16x64_i8(
            a4, __builtin_bit_cast(i32x4, B3), acc[g][3], 0, 0, 0);
      }
    }
#pragma unroll
    for (int g = 0; g < 4; ++g) aC[g] = aN[g];
    __syncthreads();
  }

  // epilogue: scale by rsqrt(cnt)/256, store bf16 partial (relu deferred)
  __hip_bfloat16* hp = Hp + (size_t)(ks * 2 + side) * HP_STRIDE;
#pragma unroll
  for (int g = 0; g < 4; ++g) {
    const int rowb = bm * 256 + w * 64 + g * 16 + l4 * 4;
#pragma unroll
    for (int c = 0; c < 4; ++c) {
      const int ocol = bn * 64 + c * 16 + l15;
#pragma unroll
      for (int q = 0; q < 4; ++q) {
        const int orow = rowb + q;
        if (orow < 4000) {
          const int cv = cnt[orow];
          const float s = cv > 0 ? rsqrtf((float)cv) * (1.0f / 256.0f) : 0.f;
          hp[(size_t)orow * 256 + ocol] = __float2bfloat16((float)acc[g][c][q] * s);
        }
      }
    }
  }
#undef STAGE
}

// ---------------------------------------------------------------------------
// K4: fused stage 2 — 256 thr (4 waves), 32 rows, 2-way K-split per wave pair.
//  Hsum = relu(sum of 6 partials). bf16 weights. grid 250 = 2 sides x 125.
// ---------------------------------------------------------------------------
__global__ __launch_bounds__(256) void k_out(const __hip_bfloat16* __restrict__ Hp,
                                             const float* __restrict__ usf,
                                             const float* __restrict__ vsf,
                                             const __hip_bfloat16* __restrict__ dWb,
                                             const __hip_bfloat16* __restrict__ W1b,
                                             const float* __restrict__ ub1,
                                             const float* __restrict__ vb1,
                                             const __hip_bfloat16* __restrict__ W2b,
                                             float* __restrict__ out) {
  const int bid = blockIdx.x;               // 0..249
  const int side = bid / 125, rb = bid % 125;
  const int t = threadIdx.x, w = t >> 6, l = t & 63;
  const int rowg = w >> 1, kh = w & 1;
  const int l15 = l & 15, l4 = l >> 4;
  const float* __restrict__ sf = side ? vsf : usf;
  const float* __restrict__ b1 = side ? vb1 : ub1;
  const __hip_bfloat16* __restrict__ W1 = W1b + side * (64 * 128);
  const __hip_bfloat16* __restrict__ W2 = W2b + side * (80 * 64);
  const __hip_bfloat16* __restrict__ hp = Hp + (size_t)side * HP_STRIDE;
  const int r0 = rb * 32 + rowg * 16;
  const int myrow = r0 + l15;

  __shared__ __hip_bfloat16 lf[2][16][72];
  __shared__ float ps[2][80][20];

  f32x4 oA[5] = {};
  const __hip_bfloat16* hbase = hp + (size_t)myrow * 256 + 8 * l4;

#define PHASE_B_HALF(kb) { \
  _Pragma("unroll") \
  for (int i_ = 0; i_ < 4; ++i_) { \
    const int kk_ = (kb) + i_ * 32; \
    const bf16x8 q0 = *(const bf16x8*)(hbase + kk_); \
    const bf16x8 q1 = *(const bf16x8*)(hbase + 2 * HP_STRIDE + kk_); \
    const bf16x8 q2 = *(const bf16x8*)(hbase + 4 * HP_STRIDE + kk_); \
    const bf16x8 q3 = *(const bf16x8*)(hbase + 6 * HP_STRIDE + kk_); \
    const bf16x8 q4 = *(const bf16x8*)(hbase + 8 * HP_STRIDE + kk_); \
    const bf16x8 q5 = *(const bf16x8*)(hbase + 10 * HP_STRIDE + kk_); \
    bf16x8 af; \
    _Pragma("unroll") \
    for (int j_ = 0; j_ < 8; ++j_) { \
      float hv = b2f(q0[j_]) + b2f(q1[j_]) + b2f(q2[j_]) + b2f(q3[j_]) + \
                 b2f(q4[j_]) + b2f(q5[j_]); \
      af[j_] = f2b(hv > 0.f ? hv : 0.f); \
    } \
    _Pragma("unroll") \
    for (int c_ = 0; c_ < 5; ++c_) { \
      const bf16x8 bf = *(const bf16x8*)(dWb + (c_ * 16 + l15) * 256 + kk_ + 8 * l4); \
      oA[c_] = __builtin_amdgcn_mfma_f32_16x16x32_bf16(af, bf, oA[c_], 0, 0, 0); \
    } \
  } }

  if (kh == 0) {
    // Phase A: F = relu(sf @ W1^T + b1)
    f32x4 fA[4] = {};
#pragma unroll
    for (int kk = 0; kk < 128; kk += 32) {
      const float* psf = sf + (size_t)myrow * 128 + kk + 8 * l4;
      const bf16x8 af = cvt8(*(const f32x4*)psf, *(const f32x4*)(psf + 4));
#pragma unroll
      for (int c = 0; c < 4; ++c) {
        const bf16x8 bf = *(const bf16x8*)(W1 + (c * 16 + l15) * 128 + kk + 8 * l4);
        fA[c] = __builtin_amdgcn_mfma_f32_16x16x32_bf16(af, bf, fA[c], 0, 0, 0);
      }
    }
#pragma unroll
    for (int c = 0; c < 4; ++c) {
      const float bv = b1[c * 16 + l15];
#pragma unroll
      for (int reg = 0; reg < 4; ++reg) {
        float v = fA[c][reg] + bv;
        lf[rowg][l4 * 4 + reg][c * 16 + l15] = __float2bfloat16(v > 0.f ? v : 0.f);
      }
    }
  } else {
    PHASE_B_HALF(128)
  }
  __syncthreads();
  if (kh == 0) {
    PHASE_B_HALF(0)
  } else {
    // W2 part: out += F @ W2^T (K=64), F from LDS
#pragma unroll
    for (int kk = 0; kk < 64; kk += 32) {
      const bf16x8 af = *(const bf16x8*)(&lf[rowg][l15][kk + 8 * l4]);
#pragma unroll
      for (int c = 0; c < 5; ++c) {
        const bf16x8 bf = *(const bf16x8*)(W2 + (c * 16 + l15) * 64 + kk + 8 * l4);
        oA[c] = __builtin_amdgcn_mfma_f32_16x16x32_bf16(af, bf, oA[c], 0, 0, 0);
      }
    }
    // store partials
#pragma unroll
    for (int c = 0; c < 5; ++c)
      *(f32x4*)&ps[rowg][c * 16 + l15][l4 * 4] = oA[c];
  }
  __syncthreads();
  if (kh == 0) {
    float* po = out + (size_t)side * (4000 * 75);
#pragma unroll
    for (int c = 0; c < 5; ++c) {
      const int oc = c * 16 + l15;
      if (oc < 75) {
        const f32x4 pv = *(const f32x4*)&ps[rowg][oc][l4 * 4];
#pragma unroll
        for (int reg = 0; reg < 4; ++reg) {
          const int orow = r0 + l4 * 4 + reg;
          const float v = oA[c][reg] + pv[reg];
          po[(size_t)orow * 75 + oc] = v > 0.f ? v : 0.f;
        }
      }
    }
  }
#undef PHASE_B_HALF
}

// ---------------------------------------------------------------------------
extern "C" void kernel_launch(void* const* d_in, const int* in_sizes, int n_in,
                              void* d_out, int out_size, void* d_ws, size_t ws_size,
                              hipStream_t stream) {
  const int* adj = (const int*)d_in[0];
  const float* usf = (const float*)d_in[1];
  const float* vsf = (const float*)d_in[2];
  const float* msgW = (const float*)d_in[3];
  const float* dW = (const float*)d_in[4];
  const float* uW1 = (const float*)d_in[5];
  const float* ub1 = (const float*)d_in[6];
  const float* uW2 = (const float*)d_in[7];
  const float* vW1 = (const float*)d_in[8];
  const float* vb1 = (const float*)d_in[9];
  const float* vW2 = (const float*)d_in[10];
  float* out = (float*)d_out;

  char* w = (char*)d_ws;
  const size_t A_BYTES = (size_t)4096 * KPH;            // 8,388,608 (packed)
  const size_t P_BYTES = (size_t)RR * MM * KP;          // 5,242,880 (int8)
  const size_t HP_BYTES = (size_t)12 * HP_STRIDE * 2;   // 24,576,000 (bf16)
  int* Nu = (int*)w;
  int* Nv = (int*)(w + 16384);
  uint8_t* Au = (uint8_t*)(w + 32768);
  uint8_t* Av = Au + A_BYTES;
  int8_t* Pu = (int8_t*)(w + 32768 + 2 * A_BYTES);
  int8_t* Pv = Pu + P_BYTES;
  __hip_bfloat16* Hp = (__hip_bfloat16*)(w + 32768 + 2 * A_BYTES + 2 * P_BYTES);
  char* wb = (char*)(Hp) + HP_BYTES;
  __hip_bfloat16* dWb = (__hip_bfloat16*)wb;                       // 40960 B
  __hip_bfloat16* W1b = (__hip_bfloat16*)(wb + 40960);             // 32768 B
  __hip_bfloat16* W2b = (__hip_bfloat16*)(wb + 40960 + 32768);     // 20480 B
  const size_t need = 32768 + 2 * A_BYTES + 2 * P_BYTES + HP_BYTES + 94208;
  if (ws_size < need) return;

  hipMemsetAsync(w, 0, 32768, stream);
  k_trans<<<dim3(64, 64), 256, 0, stream>>>(adj, Au, Av, Nu, Nv);
  k_pbuild<<<1281, 256, 0, stream>>>(msgW, Nu, Nv, Pu, Pv, dW, uW1, vW1, uW2,
                                     vW2, dWb, W1b, W2b);
  k_gemm<<<768, 256, 0, stream>>>(Au, Av, Pu, Pv, Nu, Nv, Hp);
  k_out<<<250, 256, 0, stream>>>(Hp, usf, vsf, dWb, W1b, ub1, vb1, W2b, out);
}

// Round 15
// 98.891 us; speedup vs baseline: 1.3679x; 1.3679x over previous
//
#include <hip/hip_runtime.h>
#include <hip/hip_bf16.h>
#include <stdint.h>

// Problem constants
#define NU 4000
#define NI 4000
#define RR 5
#define MM 256
#define OUTD 75
#define FDIM 128
#define KP 4096                 // padded K length (P rows)
#define KPH 2048                // packed A row bytes (KP/2)
#define HP_STRIDE 1024000       // 4000*256 elements per partial

typedef float f32x4 __attribute__((ext_vector_type(4)));
typedef int   i32x4 __attribute__((ext_vector_type(4)));
typedef short bf16x8 __attribute__((ext_vector_type(8)));

static __device__ __forceinline__ short f2b(float x) {
  __hip_bfloat16 h = __float2bfloat16(x);
  return (short)__builtin_bit_cast(unsigned short, h);
}
static __device__ __forceinline__ float b2f(short x) {
  unsigned int u = ((unsigned int)(unsigned short)x) << 16;
  return __builtin_bit_cast(float, u);
}
static __device__ __forceinline__ bf16x8 cvt8(f32x4 a, f32x4 b) {
  bf16x8 r;
  r[0] = f2b(a[0]); r[1] = f2b(a[1]); r[2] = f2b(a[2]); r[3] = f2b(a[3]);
  r[4] = f2b(b[0]); r[5] = f2b(b[1]); r[6] = f2b(b[2]); r[7] = f2b(b[3]);
  return r;
}

// ---------------------------------------------------------------------------
// K1: adj -> nibble-packed int8 (both layouts) + degree counts. (proven R13)
// ---------------------------------------------------------------------------
__global__ __launch_bounds__(256) void k_trans(const int* __restrict__ adj,
                                               uint8_t* __restrict__ a8p,
                                               uint8_t* __restrict__ a8tp,
                                               int* __restrict__ Nu,
                                               int* __restrict__ Nv) {
  __shared__ int8_t lp[64][68];   // direct:     lp[u_local][i_local]
  __shared__ int8_t lt[64][68];   // transposed: lt[i_local][u_local]
  __shared__ int rowc[64];
  __shared__ int colp[4][64];
  const int i0 = blockIdx.x * 64;
  const int u0 = blockIdx.y * 64;
  const int t = threadIdx.x;
  const int w = t >> 6, lane = t & 63;
  int mycol = 0;
  for (int rep = 0; rep < 16; rep++) {
    const int r = rep * 4 + w;
    const int u = u0 + r, i = i0 + lane;
    int a = (u < NU && i < NI) ? adj[(size_t)u * NI + i] : 0;
    const int nz = (a > 0) ? 1 : 0;
    unsigned long long bal = __ballot(nz);
    if (lane == 0) rowc[r] = (int)__popcll(bal);
    mycol += nz;
    lp[r][lane] = (int8_t)a;
    lt[lane][r] = (int8_t)a;
  }
  colp[w][lane] = mycol;
  __syncthreads();
  // phase 2: thread -> (row r = t>>2, 16-col chunk c = t&3); pack 16 vals -> 8B
  {
    const int r = t >> 2, c = t & 3;
    const uint32_t* xp = (const uint32_t*)(&lp[r][c * 16]);
    const uint32_t* xt = (const uint32_t*)(&lt[r][c * 16]);
    uint32_t t0, t1, t2, t3, w0, w1;
    t0 = xp[0] | (xp[0] >> 4); t1 = xp[1] | (xp[1] >> 4);
    t2 = xp[2] | (xp[2] >> 4); t3 = xp[3] | (xp[3] >> 4);
    w0 = __builtin_amdgcn_perm(t1, t0, 0x06040200u);
    w1 = __builtin_amdgcn_perm(t3, t2, 0x06040200u);
    *(uint2*)(a8p + (size_t)(u0 + r) * KPH + (i0 >> 1) + c * 8) = make_uint2(w0, w1);
    t0 = xt[0] | (xt[0] >> 4); t1 = xt[1] | (xt[1] >> 4);
    t2 = xt[2] | (xt[2] >> 4); t3 = xt[3] | (xt[3] >> 4);
    w0 = __builtin_amdgcn_perm(t1, t0, 0x06040200u);
    w1 = __builtin_amdgcn_perm(t3, t2, 0x06040200u);
    *(uint2*)(a8tp + (size_t)(i0 + r) * KPH + (u0 >> 1) + c * 8) = make_uint2(w0, w1);
  }
  if (t < 64) {
    const int cc = colp[0][t] + colp[1][t] + colp[2][t] + colp[3][t];
    if (i0 + t < NI && cc) atomicAdd(&Nv[i0 + t], cc);
    if (u0 + t < NU && rowc[t]) atomicAdd(&Nu[u0 + t], rowc[t]);
  }
}

// ---------------------------------------------------------------------------
// K2: P build (int8, x256 scale), vectorized, perm folded into pack. (R13)
// ---------------------------------------------------------------------------
__global__ __launch_bounds__(256) void k_pbuild(const float* __restrict__ msgW,
                                                const int* __restrict__ Nu,
                                                const int* __restrict__ Nv,
                                                int8_t* __restrict__ Pu,
                                                int8_t* __restrict__ Pv) {
  const int b = blockIdx.x;                 // r*256 + m
  const float* src = msgW + (size_t)b * (NU + NI);
#pragma unroll
  for (int it = 0; it < 2; ++it) {
    const int base = (threadIdx.x + it * 256) * 8;     // 0..4088, 8-aligned
    uint32_t lou = 0, hiu = 0, lov = 0, hiv = 0;
    if (base < NU) {                                    // NU = 8*500
      const f32x4 v0 = *(const f32x4*)(src + base);
      const f32x4 v1 = *(const f32x4*)(src + base + 4);
      const f32x4 u0 = *(const f32x4*)(src + NU + base);
      const f32x4 u1 = *(const f32x4*)(src + NU + base + 4);
      const int4 cu0 = *(const int4*)(Nu + base);
      const int4 cu1 = *(const int4*)(Nu + base + 4);
      const int4 cv0 = *(const int4*)(Nv + base);
      const int4 cv1 = *(const int4*)(Nv + base + 4);
      float qv[8], qu[8];
      const int cus[8] = {cu0.x, cu0.y, cu0.z, cu0.w, cu1.x, cu1.y, cu1.z, cu1.w};
      const int cvs[8] = {cv0.x, cv0.y, cv0.z, cv0.w, cv1.x, cv1.y, cv1.z, cv1.w};
      const float vs[8] = {v0[0], v0[1], v0[2], v0[3], v1[0], v1[1], v1[2], v1[3]};
      const float us[8] = {u0[0], u0[1], u0[2], u0[3], u1[0], u1[1], u1[2], u1[3]};
#pragma unroll
      for (int j = 0; j < 8; ++j) {
        const float su = cus[j] > 0 ? rsqrtf((float)cus[j]) * 256.0f : 0.f;
        const float sv = cvs[j] > 0 ? rsqrtf((float)cvs[j]) * 256.0f : 0.f;
        qv[j] = fminf(fmaxf(vs[j] * su, -127.f), 127.f);
        qu[j] = fminf(fmaxf(us[j] * sv, -127.f), 127.f);
      }
      uint32_t bv[8], bu[8];
#pragma unroll
      for (int j = 0; j < 8; ++j) {
        bv[j] = (uint32_t)(uint8_t)(int8_t)__float2int_rn(qv[j]);
        bu[j] = (uint32_t)(uint8_t)(int8_t)__float2int_rn(qu[j]);
      }
      lov = bv[0] | (bv[2] << 8) | (bv[4] << 16) | (bv[6] << 24);
      hiv = bv[1] | (bv[3] << 8) | (bv[5] << 16) | (bv[7] << 24);
      lou = bu[0] | (bu[2] << 8) | (bu[4] << 16) | (bu[6] << 24);
      hiu = bu[1] | (bu[3] << 8) | (bu[5] << 16) | (bu[7] << 24);
    }
    *(uint2*)(Pv + (size_t)b * KP + base) = make_uint2(lov, hiv);
    *(uint2*)(Pu + (size_t)b * KP + base) = make_uint2(lou, hiu);
  }
}

// ---------------------------------------------------------------------------
// K2b: one-time weight conversion f32 -> bf16 (zero-padded rows), 64 blocks
//  grid-stride (proven R13 — NOT folded into a single straggler block).
// ---------------------------------------------------------------------------
__global__ __launch_bounds__(256) void k_wcvt(const float* __restrict__ dW,
                                              const float* __restrict__ uW1,
                                              const float* __restrict__ vW1,
                                              const float* __restrict__ uW2,
                                              const float* __restrict__ vW2,
                                              __hip_bfloat16* __restrict__ dWb,
                                              __hip_bfloat16* __restrict__ W1b,
                                              __hip_bfloat16* __restrict__ W2b) {
  const int tid = blockIdx.x * 256 + threadIdx.x;
  const int stride = gridDim.x * 256;
  for (int idx = tid; idx < 80 * 256; idx += stride) {
    const int oc = idx >> 8, k = idx & 255;
    dWb[idx] = __float2bfloat16(oc < 75 ? dW[oc * 256 + k] : 0.f);
  }
  for (int idx = tid; idx < 2 * 64 * 128; idx += stride) {
    const int s = idx >> 13, r = idx & 8191;
    W1b[idx] = __float2bfloat16(s ? vW1[r] : uW1[r]);
  }
  for (int idx = tid; idx < 2 * 80 * 64; idx += stride) {
    const int s = idx / 5120, r = idx % 5120;
    const int oc = r >> 6, k = r & 63;
    const float* W2 = s ? vW2 : uW2;
    W2b[idx] = __float2bfloat16(oc < 75 ? W2[oc * 64 + k] : 0.f);
  }
}

// ---------------------------------------------------------------------------
// K3: one-hot i8 MFMA GEMM — 64-col waves (density-first, R14 — kept).
//  - 256 thr = 4 waves, block tile 256r x 64c, BK=64, 16x16x64 MFMA.
//  - Per step per wave: 80 perms -> 80 MFMA (6.5:1 cycles vs 2:1 in R10/R13).
//  - B tile [5r][4chunk][16c][64k] = 20KB dbuf (40KB LDS); zero-conflict maps.
//  - 3 blocks/CU (grid 768 = 2 sides x 4 bn x 6 ks x 16 bm).
//  - R10-proven lockstep schedule: STAGE(next)+A-prefetch+compute+syncthreads.
// ---------------------------------------------------------------------------
#define GLOAD_LDS(g, s) __builtin_amdgcn_global_load_lds( \
    (const __attribute__((address_space(1))) uint32_t*)(g), \
    (__attribute__((address_space(3))) uint32_t*)(s), 16, 0, 0)

static __device__ __forceinline__ uint32_t ohp(uint32_t sel, int r) {
  // one-hot i8: result byte = 0x01 iff input byte == r+1 (inputs 0..5)
  const uint32_t TL[5] = {0x00000100u, 0x00010000u, 0x01000000u, 0u, 0u};
  const uint32_t TH[5] = {0u, 0u, 0u, 0x00000001u, 0x00000100u};
  return __builtin_amdgcn_perm(TH[r], TL[r], sel);
}

__global__ __launch_bounds__(256, 3) void k_gemm(const uint8_t* __restrict__ Au,
                                                 const uint8_t* __restrict__ Av,
                                                 const int8_t* __restrict__ Pu,
                                                 const int8_t* __restrict__ Pv,
                                                 const int* __restrict__ Nu,
                                                 const int* __restrict__ Nv,
                                                 __hip_bfloat16* __restrict__ Hp) {
  __shared__ __attribute__((aligned(16))) char Bls[2][20480];

  const int bid = blockIdx.x;
  const int side = bid & 1;
  const int bn = (bid >> 1) & 3;                   // 0..3 (64-col slices)
  const int rest = bid >> 3;                       // 0..95
  const int ks = rest % 6;
  const int bm = rest / 6;                         // 0..15 (256-row tiles)
  const uint8_t* __restrict__ A8 = side ? Av : Au;
  const int8_t* __restrict__ P  = side ? Pv : Pu;
  const int* __restrict__ cnt = side ? Nv : Nu;
  const int kbeg = (ks < 4) ? ks * 704 : 2816 + (ks - 4) * 640;
  const int nst = (ks < 4) ? 11 : 10;              // steps of 64

  const int t = threadIdx.x;
  const int w = t >> 6, l = t & 63;
  const int l15 = l & 15, l4 = l >> 4;

  // staging: 20 gload_lds per block, 5 per wave (n = w*5+i).
  uint32_t soff[5], ldst[5];
  {
    const uint32_t jsrc = (uint32_t)((l & 3) ^ ((l >> 3) & 3));
#pragma unroll
    for (int i = 0; i < 5; ++i) {
      const int n = w * 5 + i;
      const int r = n >> 2, chunk = n & 3;
      const int colg = bn * 64 + chunk * 16 + (l >> 2);
      soff[i] = (uint32_t)(r * 256 + colg) * KP + jsrc * 16u;
      ldst[i] = (uint32_t)(n << 10);
    }
  }
#define STAGE(bi, kk) { _Pragma("unroll") \
  for (int i_ = 0; i_ < 5; ++i_) \
    GLOAD_LDS(P + soff[i_] + (uint32_t)(kk), &Bls[bi][0] + ldst[i_]); }

  // B read base: frag(r,c) at r*4096 + c*1024 + l15*64 + ((l4^((l15>>1)&3))<<4)
  const uint32_t rbase = (uint32_t)(l15 * 64) +
                         ((uint32_t)(l4 ^ ((l15 >> 1) & 3)) << 4);

  // A: packed byte offset per 16-row frag g (rows bm*256 + w*64 + g*16 + l15)
  uint32_t paoff[4];
#pragma unroll
  for (int g = 0; g < 4; ++g)
    paoff[g] = (uint32_t)(bm * 256 + w * 64 + g * 16 + l15) * KPH + l4 * 8;

  i32x4 acc[4][4] = {};
  uint2 aC[4], aN[4];

  STAGE(0, kbeg);
#pragma unroll
  for (int g = 0; g < 4; ++g)
    aC[g] = *(const uint2*)(A8 + paoff[g] + (kbeg >> 1));
  __syncthreads();

  for (int st = 0; st < nst; ++st) {
    const int kk = kbeg + st * 64;
    if (st + 1 < nst) {
      STAGE((st & 1) ^ 1, kk + 64);
#pragma unroll
      for (int g = 0; g < 4; ++g)
        aN[g] = *(const uint2*)(A8 + paoff[g] + ((kk + 64) >> 1));
    }
    // unpack nibbles -> 4 byte-dwords per frag (k-order matches P permutation)
    uint32_t ud[4][4];
#pragma unroll
    for (int g = 0; g < 4; ++g) {
      ud[g][0] = aC[g].x & 0x0F0F0F0Fu;
      ud[g][1] = (aC[g].x >> 4) & 0x0F0F0F0Fu;
      ud[g][2] = aC[g].y & 0x0F0F0F0Fu;
      ud[g][3] = (aC[g].y >> 4) & 0x0F0F0F0Fu;
    }
    const char* lb = &Bls[st & 1][0];
#pragma unroll
    for (int r = 0; r < 5; ++r) {
      const uint4 B0 = *(const uint4*)(lb + r * 4096 + rbase);
      const uint4 B1 = *(const uint4*)(lb + r * 4096 + rbase + 1024);
      const uint4 B2 = *(const uint4*)(lb + r * 4096 + rbase + 2048);
      const uint4 B3 = *(const uint4*)(lb + r * 4096 + rbase + 3072);
#pragma unroll
      for (int g = 0; g < 4; ++g) {
        uint4 af;
        af.x = ohp(ud[g][0], r); af.y = ohp(ud[g][1], r);
        af.z = ohp(ud[g][2], r); af.w = ohp(ud[g][3], r);
        const i32x4 a4 = __builtin_bit_cast(i32x4, af);
        acc[g][0] = __builtin_amdgcn_mfma_i32_16x16x64_i8(
            a4, __builtin_bit_cast(i32x4, B0), acc[g][0], 0, 0, 0);
        acc[g][1] = __builtin_amdgcn_mfma_i32_16x16x64_i8(
            a4, __builtin_bit_cast(i32x4, B1), acc[g][1], 0, 0, 0);
        acc[g][2] = __builtin_amdgcn_mfma_i32_16x16x64_i8(
            a4, __builtin_bit_cast(i32x4, B2), acc[g][2], 0, 0, 0);
        acc[g][3] = __builtin_amdgcn_mfma_i32_16x16x64_i8(
            a4, __builtin_bit_cast(i32x4, B3), acc[g][3], 0, 0, 0);
      }
    }
#pragma unroll
    for (int g = 0; g < 4; ++g) aC[g] = aN[g];
    __syncthreads();
  }

  // epilogue: scale by rsqrt(cnt)/256, store bf16 partial (relu deferred)
  __hip_bfloat16* hp = Hp + (size_t)(ks * 2 + side) * HP_STRIDE;
#pragma unroll
  for (int g = 0; g < 4; ++g) {
    const int rowb = bm * 256 + w * 64 + g * 16 + l4 * 4;
#pragma unroll
    for (int c = 0; c < 4; ++c) {
      const int ocol = bn * 64 + c * 16 + l15;
#pragma unroll
      for (int q = 0; q < 4; ++q) {
        const int orow = rowb + q;
        if (orow < 4000) {
          const int cv = cnt[orow];
          const float s = cv > 0 ? rsqrtf((float)cv) * (1.0f / 256.0f) : 0.f;
          hp[(size_t)orow * 256 + ocol] = __float2bfloat16((float)acc[g][c][q] * s);
        }
      }
    }
  }
#undef STAGE
}

// ---------------------------------------------------------------------------
// K4: fused stage 2 — 256 thr (4 waves), 32 rows, 2-way K-split per wave pair.
//  Hsum = relu(sum of 6 partials). bf16 weights. grid 250 = 2 sides x 125.
// ---------------------------------------------------------------------------
__global__ __launch_bounds__(256) void k_out(const __hip_bfloat16* __restrict__ Hp,
                                             const float* __restrict__ usf,
                                             const float* __restrict__ vsf,
                                             const __hip_bfloat16* __restrict__ dWb,
                                             const __hip_bfloat16* __restrict__ W1b,
                                             const float* __restrict__ ub1,
                                             const float* __restrict__ vb1,
                                             const __hip_bfloat16* __restrict__ W2b,
                                             float* __restrict__ out) {
  const int bid = blockIdx.x;               // 0..249
  const int side = bid / 125, rb = bid % 125;
  const int t = threadIdx.x, w = t >> 6, l = t & 63;
  const int rowg = w >> 1, kh = w & 1;
  const int l15 = l & 15, l4 = l >> 4;
  const float* __restrict__ sf = side ? vsf : usf;
  const float* __restrict__ b1 = side ? vb1 : ub1;
  const __hip_bfloat16* __restrict__ W1 = W1b + side * (64 * 128);
  const __hip_bfloat16* __restrict__ W2 = W2b + side * (80 * 64);
  const __hip_bfloat16* __restrict__ hp = Hp + (size_t)side * HP_STRIDE;
  const int r0 = rb * 32 + rowg * 16;
  const int myrow = r0 + l15;

  __shared__ __hip_bfloat16 lf[2][16][72];
  __shared__ float ps[2][80][20];

  f32x4 oA[5] = {};
  const __hip_bfloat16* hbase = hp + (size_t)myrow * 256 + 8 * l4;

#define PHASE_B_HALF(kb) { \
  _Pragma("unroll") \
  for (int i_ = 0; i_ < 4; ++i_) { \
    const int kk_ = (kb) + i_ * 32; \
    const bf16x8 q0 = *(const bf16x8*)(hbase + kk_); \
    const bf16x8 q1 = *(const bf16x8*)(hbase + 2 * HP_STRIDE + kk_); \
    const bf16x8 q2 = *(const bf16x8*)(hbase + 4 * HP_STRIDE + kk_); \
    const bf16x8 q3 = *(const bf16x8*)(hbase + 6 * HP_STRIDE + kk_); \
    const bf16x8 q4 = *(const bf16x8*)(hbase + 8 * HP_STRIDE + kk_); \
    const bf16x8 q5 = *(const bf16x8*)(hbase + 10 * HP_STRIDE + kk_); \
    bf16x8 af; \
    _Pragma("unroll") \
    for (int j_ = 0; j_ < 8; ++j_) { \
      float hv = b2f(q0[j_]) + b2f(q1[j_]) + b2f(q2[j_]) + b2f(q3[j_]) + \
                 b2f(q4[j_]) + b2f(q5[j_]); \
      af[j_] = f2b(hv > 0.f ? hv : 0.f); \
    } \
    _Pragma("unroll") \
    for (int c_ = 0; c_ < 5; ++c_) { \
      const bf16x8 bf = *(const bf16x8*)(dWb + (c_ * 16 + l15) * 256 + kk_ + 8 * l4); \
      oA[c_] = __builtin_amdgcn_mfma_f32_16x16x32_bf16(af, bf, oA[c_], 0, 0, 0); \
    } \
  } }

  if (kh == 0) {
    // Phase A: F = relu(sf @ W1^T + b1)
    f32x4 fA[4] = {};
#pragma unroll
    for (int kk = 0; kk < 128; kk += 32) {
      const float* psf = sf + (size_t)myrow * 128 + kk + 8 * l4;
      const bf16x8 af = cvt8(*(const f32x4*)psf, *(const f32x4*)(psf + 4));
#pragma unroll
      for (int c = 0; c < 4; ++c) {
        const bf16x8 bf = *(const bf16x8*)(W1 + (c * 16 + l15) * 128 + kk + 8 * l4);
        fA[c] = __builtin_amdgcn_mfma_f32_16x16x32_bf16(af, bf, fA[c], 0, 0, 0);
      }
    }
#pragma unroll
    for (int c = 0; c < 4; ++c) {
      const float bv = b1[c * 16 + l15];
#pragma unroll
      for (int reg = 0; reg < 4; ++reg) {
        float v = fA[c][reg] + bv;
        lf[rowg][l4 * 4 + reg][c * 16 + l15] = __float2bfloat16(v > 0.f ? v : 0.f);
      }
    }
  } else {
    PHASE_B_HALF(128)
  }
  __syncthreads();
  if (kh == 0) {
    PHASE_B_HALF(0)
  } else {
    // W2 part: out += F @ W2^T (K=64), F from LDS
#pragma unroll
    for (int kk = 0; kk < 64; kk += 32) {
      const bf16x8 af = *(const bf16x8*)(&lf[rowg][l15][kk + 8 * l4]);
#pragma unroll
      for (int c = 0; c < 5; ++c) {
        const bf16x8 bf = *(const bf16x8*)(W2 + (c * 16 + l15) * 64 + kk + 8 * l4);
        oA[c] = __builtin_amdgcn_mfma_f32_16x16x32_bf16(af, bf, oA[c], 0, 0, 0);
      }
    }
    // store partials
#pragma unroll
    for (int c = 0; c < 5; ++c)
      *(f32x4*)&ps[rowg][c * 16 + l15][l4 * 4] = oA[c];
  }
  __syncthreads();
  if (kh == 0) {
    float* po = out + (size_t)side * (4000 * 75);
#pragma unroll
    for (int c = 0; c < 5; ++c) {
      const int oc = c * 16 + l15;
      if (oc < 75) {
        const f32x4 pv = *(const f32x4*)&ps[rowg][oc][l4 * 4];
#pragma unroll
        for (int reg = 0; reg < 4; ++reg) {
          const int orow = r0 + l4 * 4 + reg;
          const float v = oA[c][reg] + pv[reg];
          po[(size_t)orow * 75 + oc] = v > 0.f ? v : 0.f;
        }
      }
    }
  }
#undef PHASE_B_HALF
}

// ---------------------------------------------------------------------------
extern "C" void kernel_launch(void* const* d_in, const int* in_sizes, int n_in,
                              void* d_out, int out_size, void* d_ws, size_t ws_size,
                              hipStream_t stream) {
  const int* adj = (const int*)d_in[0];
  const float* usf = (const float*)d_in[1];
  const float* vsf = (const float*)d_in[2];
  const float* msgW = (const float*)d_in[3];
  const float* dW = (const float*)d_in[4];
  const float* uW1 = (const float*)d_in[5];
  const float* ub1 = (const float*)d_in[6];
  const float* uW2 = (const float*)d_in[7];
  const float* vW1 = (const float*)d_in[8];
  const float* vb1 = (const float*)d_in[9];
  const float* vW2 = (const float*)d_in[10];
  float* out = (float*)d_out;

  char* w = (char*)d_ws;
  const size_t A_BYTES = (size_t)4096 * KPH;            // 8,388,608 (packed)
  const size_t P_BYTES = (size_t)RR * MM * KP;          // 5,242,880 (int8)
  const size_t HP_BYTES = (size_t)12 * HP_STRIDE * 2;   // 24,576,000 (bf16)
  int* Nu = (int*)w;
  int* Nv = (int*)(w + 16384);
  uint8_t* Au = (uint8_t*)(w + 32768);
  uint8_t* Av = Au + A_BYTES;
  int8_t* Pu = (int8_t*)(w + 32768 + 2 * A_BYTES);
  int8_t* Pv = Pu + P_BYTES;
  __hip_bfloat16* Hp = (__hip_bfloat16*)(w + 32768 + 2 * A_BYTES + 2 * P_BYTES);
  char* wb = (char*)(Hp) + HP_BYTES;
  __hip_bfloat16* dWb = (__hip_bfloat16*)wb;                       // 40960 B
  __hip_bfloat16* W1b = (__hip_bfloat16*)(wb + 40960);             // 32768 B
  __hip_bfloat16* W2b = (__hip_bfloat16*)(wb + 40960 + 32768);     // 20480 B
  const size_t need = 32768 + 2 * A_BYTES + 2 * P_BYTES + HP_BYTES + 94208;
  if (ws_size < need) return;

  hipMemsetAsync(w, 0, 32768, stream);
  k_wcvt<<<64, 256, 0, stream>>>(dW, uW1, vW1, uW2, vW2, dWb, W1b, W2b);
  k_trans<<<dim3(64, 64), 256, 0, stream>>>(adj, Au, Av, Nu, Nv);
  k_pbuild<<<1280, 256, 0, stream>>>(msgW, Nu, Nv, Pu, Pv);
  k_gemm<<<768, 256, 0, stream>>>(Au, Av, Pu, Pv, Nu, Nv, Hp);
  k_out<<<250, 256, 0, stream>>>(Hp, usf, vsf, dWb, W1b, ub1, vb1, W2b, out);
}

// Round 17
// 93.781 us; speedup vs baseline: 1.4424x; 1.0545x over previous
//
#include <hip/hip_runtime.h>
#include <hip/hip_bf16.h>
#include <stdint.h>

// Problem constants
#define NU 4000
#define NI 4000
#define RR 5
#define MM 256
#define OUTD 75
#define FDIM 128
#define KP 4096                 // padded K length (P rows)
#define KPH 2048                // packed A row bytes (KP/2)
#define HP_STRIDE 1024000       // 4000*256 elements per partial

typedef float f32x4 __attribute__((ext_vector_type(4)));
typedef int   i32x4 __attribute__((ext_vector_type(4)));
typedef short bf16x8 __attribute__((ext_vector_type(8)));

static __device__ __forceinline__ short f2b(float x) {
  __hip_bfloat16 h = __float2bfloat16(x);
  return (short)__builtin_bit_cast(unsigned short, h);
}
static __device__ __forceinline__ float b2f(short x) {
  unsigned int u = ((unsigned int)(unsigned short)x) << 16;
  return __builtin_bit_cast(float, u);
}
static __device__ __forceinline__ bf16x8 cvt8(f32x4 a, f32x4 b) {
  bf16x8 r;
  r[0] = f2b(a[0]); r[1] = f2b(a[1]); r[2] = f2b(a[2]); r[3] = f2b(a[3]);
  r[4] = f2b(b[0]); r[5] = f2b(b[1]); r[6] = f2b(b[2]); r[7] = f2b(b[3]);
  return r;
}

// ---------------------------------------------------------------------------
// K1: adj -> nibble-packed int8 (both layouts) + degree counts. (proven R13)
// ---------------------------------------------------------------------------
__global__ __launch_bounds__(256) void k_trans(const int* __restrict__ adj,
                                               uint8_t* __restrict__ a8p,
                                               uint8_t* __restrict__ a8tp,
                                               int* __restrict__ Nu,
                                               int* __restrict__ Nv) {
  __shared__ int8_t lp[64][68];   // direct:     lp[u_local][i_local]
  __shared__ int8_t lt[64][68];   // transposed: lt[i_local][u_local]
  __shared__ int rowc[64];
  __shared__ int colp[4][64];
  const int i0 = blockIdx.x * 64;
  const int u0 = blockIdx.y * 64;
  const int t = threadIdx.x;
  const int w = t >> 6, lane = t & 63;
  int mycol = 0;
  for (int rep = 0; rep < 16; rep++) {
    const int r = rep * 4 + w;
    const int u = u0 + r, i = i0 + lane;
    int a = (u < NU && i < NI) ? adj[(size_t)u * NI + i] : 0;
    const int nz = (a > 0) ? 1 : 0;
    unsigned long long bal = __ballot(nz);
    if (lane == 0) rowc[r] = (int)__popcll(bal);
    mycol += nz;
    lp[r][lane] = (int8_t)a;
    lt[lane][r] = (int8_t)a;
  }
  colp[w][lane] = mycol;
  __syncthreads();
  // phase 2: thread -> (row r = t>>2, 16-col chunk c = t&3); pack 16 vals -> 8B
  {
    const int r = t >> 2, c = t & 3;
    const uint32_t* xp = (const uint32_t*)(&lp[r][c * 16]);
    const uint32_t* xt = (const uint32_t*)(&lt[r][c * 16]);
    uint32_t t0, t1, t2, t3, w0, w1;
    t0 = xp[0] | (xp[0] >> 4); t1 = xp[1] | (xp[1] >> 4);
    t2 = xp[2] | (xp[2] >> 4); t3 = xp[3] | (xp[3] >> 4);
    w0 = __builtin_amdgcn_perm(t1, t0, 0x06040200u);
    w1 = __builtin_amdgcn_perm(t3, t2, 0x06040200u);
    *(uint2*)(a8p + (size_t)(u0 + r) * KPH + (i0 >> 1) + c * 8) = make_uint2(w0, w1);
    t0 = xt[0] | (xt[0] >> 4); t1 = xt[1] | (xt[1] >> 4);
    t2 = xt[2] | (xt[2] >> 4); t3 = xt[3] | (xt[3] >> 4);
    w0 = __builtin_amdgcn_perm(t1, t0, 0x06040200u);
    w1 = __builtin_amdgcn_perm(t3, t2, 0x06040200u);
    *(uint2*)(a8tp + (size_t)(i0 + r) * KPH + (u0 >> 1) + c * 8) = make_uint2(w0, w1);
  }
  if (t < 64) {
    const int cc = colp[0][t] + colp[1][t] + colp[2][t] + colp[3][t];
    if (i0 + t < NI && cc) atomicAdd(&Nv[i0 + t], cc);
    if (u0 + t < NU && rowc[t]) atomicAdd(&Nu[u0 + t], rowc[t]);
  }
}

// ---------------------------------------------------------------------------
// K2: P build (int8, x256 scale), vectorized, perm folded into pack. (R13)
// ---------------------------------------------------------------------------
__global__ __launch_bounds__(256) void k_pbuild(const float* __restrict__ msgW,
                                                const int* __restrict__ Nu,
                                                const int* __restrict__ Nv,
                                                int8_t* __restrict__ Pu,
                                                int8_t* __restrict__ Pv) {
  const int b = blockIdx.x;                 // r*256 + m
  const float* src = msgW + (size_t)b * (NU + NI);
#pragma unroll
  for (int it = 0; it < 2; ++it) {
    const int base = (threadIdx.x + it * 256) * 8;     // 0..4088, 8-aligned
    uint32_t lou = 0, hiu = 0, lov = 0, hiv = 0;
    if (base < NU) {                                    // NU = 8*500
      const f32x4 v0 = *(const f32x4*)(src + base);
      const f32x4 v1 = *(const f32x4*)(src + base + 4);
      const f32x4 u0 = *(const f32x4*)(src + NU + base);
      const f32x4 u1 = *(const f32x4*)(src + NU + base + 4);
      const int4 cu0 = *(const int4*)(Nu + base);
      const int4 cu1 = *(const int4*)(Nu + base + 4);
      const int4 cv0 = *(const int4*)(Nv + base);
      const int4 cv1 = *(const int4*)(Nv + base + 4);
      float qv[8], qu[8];
      const int cus[8] = {cu0.x, cu0.y, cu0.z, cu0.w, cu1.x, cu1.y, cu1.z, cu1.w};
      const int cvs[8] = {cv0.x, cv0.y, cv0.z, cv0.w, cv1.x, cv1.y, cv1.z, cv1.w};
      const float vs[8] = {v0[0], v0[1], v0[2], v0[3], v1[0], v1[1], v1[2], v1[3]};
      const float us[8] = {u0[0], u0[1], u0[2], u0[3], u1[0], u1[1], u1[2], u1[3]};
#pragma unroll
      for (int j = 0; j < 8; ++j) {
        const float su = cus[j] > 0 ? rsqrtf((float)cus[j]) * 256.0f : 0.f;
        const float sv = cvs[j] > 0 ? rsqrtf((float)cvs[j]) * 256.0f : 0.f;
        qv[j] = fminf(fmaxf(vs[j] * su, -127.f), 127.f);
        qu[j] = fminf(fmaxf(us[j] * sv, -127.f), 127.f);
      }
      uint32_t bv[8], bu[8];
#pragma unroll
      for (int j = 0; j < 8; ++j) {
        bv[j] = (uint32_t)(uint8_t)(int8_t)__float2int_rn(qv[j]);
        bu[j] = (uint32_t)(uint8_t)(int8_t)__float2int_rn(qu[j]);
      }
      lov = bv[0] | (bv[2] << 8) | (bv[4] << 16) | (bv[6] << 24);
      hiv = bv[1] | (bv[3] << 8) | (bv[5] << 16) | (bv[7] << 24);
      lou = bu[0] | (bu[2] << 8) | (bu[4] << 16) | (bu[6] << 24);
      hiu = bu[1] | (bu[3] << 8) | (bu[5] << 16) | (bu[7] << 24);
    }
    *(uint2*)(Pv + (size_t)b * KP + base) = make_uint2(lov, hiv);
    *(uint2*)(Pu + (size_t)b * KP + base) = make_uint2(lou, hiu);
  }
}

// ---------------------------------------------------------------------------
// K2b: one-time weight conversion f32 -> bf16 (zero-padded rows), 64 blocks.
// ---------------------------------------------------------------------------
__global__ __launch_bounds__(256) void k_wcvt(const float* __restrict__ dW,
                                              const float* __restrict__ uW1,
                                              const float* __restrict__ vW1,
                                              const float* __restrict__ uW2,
                                              const float* __restrict__ vW2,
                                              __hip_bfloat16* __restrict__ dWb,
                                              __hip_bfloat16* __restrict__ W1b,
                                              __hip_bfloat16* __restrict__ W2b) {
  const int tid = blockIdx.x * 256 + threadIdx.x;
  const int stride = gridDim.x * 256;
  for (int idx = tid; idx < 80 * 256; idx += stride) {
    const int oc = idx >> 8, k = idx & 255;
    dWb[idx] = __float2bfloat16(oc < 75 ? dW[oc * 256 + k] : 0.f);
  }
  for (int idx = tid; idx < 2 * 64 * 128; idx += stride) {
    const int s = idx >> 13, r = idx & 8191;
    W1b[idx] = __float2bfloat16(s ? vW1[r] : uW1[r]);
  }
  for (int idx = tid; idx < 2 * 80 * 64; idx += stride) {
    const int s = idx / 5120, r = idx % 5120;
    const int oc = r >> 6, k = r & 63;
    const float* W2 = s ? vW2 : uW2;
    W2b[idx] = __float2bfloat16(oc < 75 ? W2[oc * 64 + k] : 0.f);
  }
}

// ---------------------------------------------------------------------------
// K3: one-hot i8 MFMA GEMM — 64-col waves, occupancy-4 geometry. (R16)
//  - 256 thr = 4 waves, block tile 128r x 64c (wave = 32r x 64c), BK=64.
//  - B tile [5r][4chunk][16c][64k] = 20KB dbuf (40KB LDS); zero-conflict maps.
//  - 4 blocks/CU (grid 1024 = 2 sides x 4 bn x 4 ks x 32 bm; LDS 160KB exact).
//  - ks=4 splits of 1024k -> uniform 16 steps; 4 partials PER SIDE (8 total).
// ---------------------------------------------------------------------------
#define GLOAD_LDS(g, s) __builtin_amdgcn_global_load_lds( \
    (const __attribute__((address_space(1))) uint32_t*)(g), \
    (__attribute__((address_space(3))) uint32_t*)(s), 16, 0, 0)

static __device__ __forceinline__ uint32_t ohp(uint32_t sel, int r) {
  // one-hot i8: result byte = 0x01 iff input byte == r+1 (inputs 0..5)
  const uint32_t TL[5] = {0x00000100u, 0x00010000u, 0x01000000u, 0u, 0u};
  const uint32_t TH[5] = {0u, 0u, 0u, 0x00000001u, 0x00000100u};
  return __builtin_amdgcn_perm(TH[r], TL[r], sel);
}

__global__ __launch_bounds__(256, 4) void k_gemm(const uint8_t* __restrict__ Au,
                                                 const uint8_t* __restrict__ Av,
                                                 const int8_t* __restrict__ Pu,
                                                 const int8_t* __restrict__ Pv,
                                                 const int* __restrict__ Nu,
                                                 const int* __restrict__ Nv,
                                                 __hip_bfloat16* __restrict__ Hp) {
  __shared__ __attribute__((aligned(16))) char Bls[2][20480];

  const int bid = blockIdx.x;
  const int side = bid & 1;
  const int bn = (bid >> 1) & 3;                   // 0..3 (64-col slices)
  const int rest = bid >> 3;                       // 0..127
  const int ks = rest & 3;                         // 0..3
  const int bm = rest >> 2;                        // 0..31 (128-row tiles)
  const uint8_t* __restrict__ A8 = side ? Av : Au;
  const int8_t* __restrict__ P  = side ? Pv : Pu;
  const int* __restrict__ cnt = side ? Nv : Nu;
  const int kbeg = ks * 1024;
  const int nst = 16;                              // uniform steps of 64

  const int t = threadIdx.x;
  const int w = t >> 6, l = t & 63;
  const int l15 = l & 15, l4 = l >> 4;

  // staging: 20 gload_lds per block, 5 per wave (n = w*5+i). (proven maps)
  uint32_t soff[5], ldst[5];
  {
    const uint32_t jsrc = (uint32_t)((l & 3) ^ ((l >> 3) & 3));
#pragma unroll
    for (int i = 0; i < 5; ++i) {
      const int n = w * 5 + i;
      const int r = n >> 2, chunk = n & 3;
      const int colg = bn * 64 + chunk * 16 + (l >> 2);
      soff[i] = (uint32_t)(r * 256 + colg) * KP + jsrc * 16u;
      ldst[i] = (uint32_t)(n << 10);
    }
  }
#define STAGE(bi, kk) { _Pragma("unroll") \
  for (int i_ = 0; i_ < 5; ++i_) \
    GLOAD_LDS(P + soff[i_] + (uint32_t)(kk), &Bls[bi][0] + ldst[i_]); }

  // B read base: frag(r,c) at r*4096 + c*1024 + l15*64 + ((l4^((l15>>1)&3))<<4)
  const uint32_t rbase = (uint32_t)(l15 * 64) +
                         ((uint32_t)(l4 ^ ((l15 >> 1) & 3)) << 4);

  // A: packed byte offset per 16-row frag g (rows bm*128 + w*32 + g*16 + l15)
  uint32_t paoff[2];
#pragma unroll
  for (int g = 0; g < 2; ++g)
    paoff[g] = (uint32_t)(bm * 128 + w * 32 + g * 16 + l15) * KPH + l4 * 8;

  i32x4 acc[2][4] = {};
  uint2 aC[2], aN[2];

  STAGE(0, kbeg);
#pragma unroll
  for (int g = 0; g < 2; ++g)
    aC[g] = *(const uint2*)(A8 + paoff[g] + (kbeg >> 1));
  __syncthreads();

  for (int st = 0; st < nst; ++st) {
    const int kk = kbeg + st * 64;
    if (st + 1 < nst) {
      STAGE((st & 1) ^ 1, kk + 64);
#pragma unroll
      for (int g = 0; g < 2; ++g)
        aN[g] = *(const uint2*)(A8 + paoff[g] + ((kk + 64) >> 1));
    }
    // unpack nibbles -> 4 byte-dwords per frag (k-order matches P permutation)
    uint32_t ud[2][4];
#pragma unroll
    for (int g = 0; g < 2; ++g) {
      ud[g][0] = aC[g].x & 0x0F0F0F0Fu;
      ud[g][1] = (aC[g].x >> 4) & 0x0F0F0F0Fu;
      ud[g][2] = aC[g].y & 0x0F0F0F0Fu;
      ud[g][3] = (aC[g].y >> 4) & 0x0F0F0F0Fu;
    }
    const char* lb = &Bls[st & 1][0];
#pragma unroll
    for (int r = 0; r < 5; ++r) {
      const uint4 B0 = *(const uint4*)(lb + r * 4096 + rbase);
      const uint4 B1 = *(const uint4*)(lb + r * 4096 + rbase + 1024);
      const uint4 B2 = *(const uint4*)(lb + r * 4096 + rbase + 2048);
      const uint4 B3 = *(const uint4*)(lb + r * 4096 + rbase + 3072);
#pragma unroll
      for (int g = 0; g < 2; ++g) {
        uint4 af;
        af.x = ohp(ud[g][0], r); af.y = ohp(ud[g][1], r);
        af.z = ohp(ud[g][2], r); af.w = ohp(ud[g][3], r);
        const i32x4 a4 = __builtin_bit_cast(i32x4, af);
        acc[g][0] = __builtin_amdgcn_mfma_i32_16x16x64_i8(
            a4, __builtin_bit_cast(i32x4, B0), acc[g][0], 0, 0, 0);
        acc[g][1] = __builtin_amdgcn_mfma_i32_16x16x64_i8(
            a4, __builtin_bit_cast(i32x4, B1), acc[g][1], 0, 0, 0);
        acc[g][2] = __builtin_amdgcn_mfma_i32_16x16x64_i8(
            a4, __builtin_bit_cast(i32x4, B2), acc[g][2], 0, 0, 0);
        acc[g][3] = __builtin_amdgcn_mfma_i32_16x16x64_i8(
            a4, __builtin_bit_cast(i32x4, B3), acc[g][3], 0, 0, 0);
      }
    }
#pragma unroll
    for (int g = 0; g < 2; ++g) aC[g] = aN[g];
    __syncthreads();
  }

  // epilogue: scale by rsqrt(cnt)/256, store bf16 partial (relu deferred)
  __hip_bfloat16* hp = Hp + (size_t)(ks * 2 + side) * HP_STRIDE;
#pragma unroll
  for (int g = 0; g < 2; ++g) {
    const int rowb = bm * 128 + w * 32 + g * 16 + l4 * 4;
#pragma unroll
    for (int c = 0; c < 4; ++c) {
      const int ocol = bn * 64 + c * 16 + l15;
#pragma unroll
      for (int q = 0; q < 4; ++q) {
        const int orow = rowb + q;
        if (orow < 4000) {
          const int cv = cnt[orow];
          const float s = cv > 0 ? rsqrtf((float)cv) * (1.0f / 256.0f) : 0.f;
          hp[(size_t)orow * 256 + ocol] = __float2bfloat16((float)acc[g][c][q] * s);
        }
      }
    }
  }
#undef STAGE
}

// ---------------------------------------------------------------------------
// K4: fused stage 2 — 256 thr (4 waves), 32 rows, 2-way K-split per wave pair.
//  Hsum = relu(sum of 4 partials PER SIDE) — partial j (j=0..3) for side s
//  lives at Hp index j*2+s, i.e. per-side offsets 0,2,4,6 x HP_STRIDE.
//  (R16 bug: summed 8 offsets up to 14 x HP_STRIDE -> read past Hp. FIXED.)
// ---------------------------------------------------------------------------
__global__ __launch_bounds__(256) void k_out(const __hip_bfloat16* __restrict__ Hp,
                                             const float* __restrict__ usf,
                                             const float* __restrict__ vsf,
                                             const __hip_bfloat16* __restrict__ dWb,
                                             const __hip_bfloat16* __restrict__ W1b,
                                             const float* __restrict__ ub1,
                                             const float* __restrict__ vb1,
                                             const __hip_bfloat16* __restrict__ W2b,
                                             float* __restrict__ out) {
  const int bid = blockIdx.x;               // 0..249
  const int side = bid / 125, rb = bid % 125;
  const int t = threadIdx.x, w = t >> 6, l = t & 63;
  const int rowg = w >> 1, kh = w & 1;
  const int l15 = l & 15, l4 = l >> 4;
  const float* __restrict__ sf = side ? vsf : usf;
  const float* __restrict__ b1 = side ? vb1 : ub1;
  const __hip_bfloat16* __restrict__ W1 = W1b + side * (64 * 128);
  const __hip_bfloat16* __restrict__ W2 = W2b + side * (80 * 64);
  const __hip_bfloat16* __restrict__ hp = Hp + (size_t)side * HP_STRIDE;
  const int r0 = rb * 32 + rowg * 16;
  const int myrow = r0 + l15;

  __shared__ __hip_bfloat16 lf[2][16][72];
  __shared__ float ps[2][80][20];

  f32x4 oA[5] = {};
  const __hip_bfloat16* hbase = hp + (size_t)myrow * 256 + 8 * l4;

#define PHASE_B_HALF(kb) { \
  _Pragma("unroll") \
  for (int i_ = 0; i_ < 4; ++i_) { \
    const int kk_ = (kb) + i_ * 32; \
    const bf16x8 q0 = *(const bf16x8*)(hbase + kk_); \
    const bf16x8 q1 = *(const bf16x8*)(hbase + 2 * HP_STRIDE + kk_); \
    const bf16x8 q2 = *(const bf16x8*)(hbase + 4 * HP_STRIDE + kk_); \
    const bf16x8 q3 = *(const bf16x8*)(hbase + 6 * HP_STRIDE + kk_); \
    bf16x8 af; \
    _Pragma("unroll") \
    for (int j_ = 0; j_ < 8; ++j_) { \
      float hv = b2f(q0[j_]) + b2f(q1[j_]) + b2f(q2[j_]) + b2f(q3[j_]); \
      af[j_] = f2b(hv > 0.f ? hv : 0.f); \
    } \
    _Pragma("unroll") \
    for (int c_ = 0; c_ < 5; ++c_) { \
      const bf16x8 bf = *(const bf16x8*)(dWb + (c_ * 16 + l15) * 256 + kk_ + 8 * l4); \
      oA[c_] = __builtin_amdgcn_mfma_f32_16x16x32_bf16(af, bf, oA[c_], 0, 0, 0); \
    } \
  } }

  if (kh == 0) {
    // Phase A: F = relu(sf @ W1^T + b1)
    f32x4 fA[4] = {};
#pragma unroll
    for (int kk = 0; kk < 128; kk += 32) {
      const float* psf = sf + (size_t)myrow * 128 + kk + 8 * l4;
      const bf16x8 af = cvt8(*(const f32x4*)psf, *(const f32x4*)(psf + 4));
#pragma unroll
      for (int c = 0; c < 4; ++c) {
        const bf16x8 bf = *(const bf16x8*)(W1 + (c * 16 + l15) * 128 + kk + 8 * l4);
        fA[c] = __builtin_amdgcn_mfma_f32_16x16x32_bf16(af, bf, fA[c], 0, 0, 0);
      }
    }
#pragma unroll
    for (int c = 0; c < 4; ++c) {
      const float bv = b1[c * 16 + l15];
#pragma unroll
      for (int reg = 0; reg < 4; ++reg) {
        float v = fA[c][reg] + bv;
        lf[rowg][l4 * 4 + reg][c * 16 + l15] = __float2bfloat16(v > 0.f ? v : 0.f);
      }
    }
  } else {
    PHASE_B_HALF(128)
  }
  __syncthreads();
  if (kh == 0) {
    PHASE_B_HALF(0)
  } else {
    // W2 part: out += F @ W2^T (K=64), F from LDS
#pragma unroll
    for (int kk = 0; kk < 64; kk += 32) {
      const bf16x8 af = *(const bf16x8*)(&lf[rowg][l15][kk + 8 * l4]);
#pragma unroll
      for (int c = 0; c < 5; ++c) {
        const bf16x8 bf = *(const bf16x8*)(W2 + (c * 16 + l15) * 64 + kk + 8 * l4);
        oA[c] = __builtin_amdgcn_mfma_f32_16x16x32_bf16(af, bf, oA[c], 0, 0, 0);
      }
    }
    // store partials
#pragma unroll
    for (int c = 0; c < 5; ++c)
      *(f32x4*)&ps[rowg][c * 16 + l15][l4 * 4] = oA[c];
  }
  __syncthreads();
  if (kh == 0) {
    float* po = out + (size_t)side * (4000 * 75);
#pragma unroll
    for (int c = 0; c < 5; ++c) {
      const int oc = c * 16 + l15;
      if (oc < 75) {
        const f32x4 pv = *(const f32x4*)&ps[rowg][oc][l4 * 4];
#pragma unroll
        for (int reg = 0; reg < 4; ++reg) {
          const int orow = r0 + l4 * 4 + reg;
          const float v = oA[c][reg] + pv[reg];
          po[(size_t)orow * 75 + oc] = v > 0.f ? v : 0.f;
        }
      }
    }
  }
#undef PHASE_B_HALF
}

// ---------------------------------------------------------------------------
extern "C" void kernel_launch(void* const* d_in, const int* in_sizes, int n_in,
                              void* d_out, int out_size, void* d_ws, size_t ws_size,
                              hipStream_t stream) {
  const int* adj = (const int*)d_in[0];
  const float* usf = (const float*)d_in[1];
  const float* vsf = (const float*)d_in[2];
  const float* msgW = (const float*)d_in[3];
  const float* dW = (const float*)d_in[4];
  const float* uW1 = (const float*)d_in[5];
  const float* ub1 = (const float*)d_in[6];
  const float* uW2 = (const float*)d_in[7];
  const float* vW1 = (const float*)d_in[8];
  const float* vb1 = (const float*)d_in[9];
  const float* vW2 = (const float*)d_in[10];
  float* out = (float*)d_out;

  char* w = (char*)d_ws;
  const size_t A_BYTES = (size_t)4096 * KPH;            // 8,388,608 per side
  const size_t P_BYTES = (size_t)RR * MM * KP;          // 5,242,880 (int8)
  const size_t HP_BYTES = (size_t)8 * HP_STRIDE * 2;    // 16,384,000 (bf16)
  int* Nu = (int*)w;
  int* Nv = (int*)(w + 16384);
  uint8_t* Au = (uint8_t*)(w + 32768);
  uint8_t* Av = Au + A_BYTES;
  int8_t* Pu = (int8_t*)(w + 32768 + 2 * A_BYTES);
  int8_t* Pv = Pu + P_BYTES;
  __hip_bfloat16* Hp = (__hip_bfloat16*)(w + 32768 + 2 * A_BYTES + 2 * P_BYTES);
  char* wb = (char*)(Hp) + HP_BYTES;
  __hip_bfloat16* dWb = (__hip_bfloat16*)wb;                       // 40960 B
  __hip_bfloat16* W1b = (__hip_bfloat16*)(wb + 40960);             // 32768 B
  __hip_bfloat16* W2b = (__hip_bfloat16*)(wb + 40960 + 32768);     // 20480 B
  const size_t need = 32768 + 2 * A_BYTES + 2 * P_BYTES + HP_BYTES + 94208;
  if (ws_size < need) return;                            // ~43.8 MB

  hipMemsetAsync(w, 0, 32768, stream);
  k_wcvt<<<64, 256, 0, stream>>>(dW, uW1, vW1, uW2, vW2, dWb, W1b, W2b);
  k_trans<<<dim3(64, 64), 256, 0, stream>>>(adj, Au, Av, Nu, Nv);
  k_pbuild<<<1280, 256, 0, stream>>>(msgW, Nu, Nv, Pu, Pv);
  k_gemm<<<1024, 256, 0, stream>>>(Au, Av, Pu, Pv, Nu, Nv, Hp);
  k_out<<<250, 256, 0, stream>>>(Hp, usf, vsf, dWb, W1b, ub1, vb1, W2b, out);
}

// Round 18
// 90.118 us; speedup vs baseline: 1.5011x; 1.0406x over previous
//
#include <hip/hip_runtime.h>
#include <hip/hip_bf16.h>
#include <stdint.h>

// Problem constants
#define NU 4000
#define NI 4000
#define RR 5
#define MM 256
#define OUTD 75
#define FDIM 128
#define KP 4096                 // padded K length (P rows)
#define KPH 2048                // packed A row bytes (KP/2)
#define HP_STRIDE 1024000       // 4000*256 elements per partial

typedef float f32x4 __attribute__((ext_vector_type(4)));
typedef int   i32x4 __attribute__((ext_vector_type(4)));
typedef short bf16x8 __attribute__((ext_vector_type(8)));

static __device__ __forceinline__ short f2b(float x) {
  __hip_bfloat16 h = __float2bfloat16(x);
  return (short)__builtin_bit_cast(unsigned short, h);
}
static __device__ __forceinline__ float b2f(short x) {
  unsigned int u = ((unsigned int)(unsigned short)x) << 16;
  return __builtin_bit_cast(float, u);
}
static __device__ __forceinline__ bf16x8 cvt8(f32x4 a, f32x4 b) {
  bf16x8 r;
  r[0] = f2b(a[0]); r[1] = f2b(a[1]); r[2] = f2b(a[2]); r[3] = f2b(a[3]);
  r[4] = f2b(b[0]); r[5] = f2b(b[1]); r[6] = f2b(b[2]); r[7] = f2b(b[3]);
  return r;
}

// ---------------------------------------------------------------------------
// K1: adj -> nibble-packed int8 (both layouts) + degree counts. (proven R13)
// ---------------------------------------------------------------------------
__global__ __launch_bounds__(256) void k_trans(const int* __restrict__ adj,
                                               uint8_t* __restrict__ a8p,
                                               uint8_t* __restrict__ a8tp,
                                               int* __restrict__ Nu,
                                               int* __restrict__ Nv) {
  __shared__ int8_t lp[64][68];   // direct:     lp[u_local][i_local]
  __shared__ int8_t lt[64][68];   // transposed: lt[i_local][u_local]
  __shared__ int rowc[64];
  __shared__ int colp[4][64];
  const int i0 = blockIdx.x * 64;
  const int u0 = blockIdx.y * 64;
  const int t = threadIdx.x;
  const int w = t >> 6, lane = t & 63;
  int mycol = 0;
  for (int rep = 0; rep < 16; rep++) {
    const int r = rep * 4 + w;
    const int u = u0 + r, i = i0 + lane;
    int a = (u < NU && i < NI) ? adj[(size_t)u * NI + i] : 0;
    const int nz = (a > 0) ? 1 : 0;
    unsigned long long bal = __ballot(nz);
    if (lane == 0) rowc[r] = (int)__popcll(bal);
    mycol += nz;
    lp[r][lane] = (int8_t)a;
    lt[lane][r] = (int8_t)a;
  }
  colp[w][lane] = mycol;
  __syncthreads();
  // phase 2: thread -> (row r = t>>2, 16-col chunk c = t&3); pack 16 vals -> 8B
  {
    const int r = t >> 2, c = t & 3;
    const uint32_t* xp = (const uint32_t*)(&lp[r][c * 16]);
    const uint32_t* xt = (const uint32_t*)(&lt[r][c * 16]);
    uint32_t t0, t1, t2, t3, w0, w1;
    t0 = xp[0] | (xp[0] >> 4); t1 = xp[1] | (xp[1] >> 4);
    t2 = xp[2] | (xp[2] >> 4); t3 = xp[3] | (xp[3] >> 4);
    w0 = __builtin_amdgcn_perm(t1, t0, 0x06040200u);
    w1 = __builtin_amdgcn_perm(t3, t2, 0x06040200u);
    *(uint2*)(a8p + (size_t)(u0 + r) * KPH + (i0 >> 1) + c * 8) = make_uint2(w0, w1);
    t0 = xt[0] | (xt[0] >> 4); t1 = xt[1] | (xt[1] >> 4);
    t2 = xt[2] | (xt[2] >> 4); t3 = xt[3] | (xt[3] >> 4);
    w0 = __builtin_amdgcn_perm(t1, t0, 0x06040200u);
    w1 = __builtin_amdgcn_perm(t3, t2, 0x06040200u);
    *(uint2*)(a8tp + (size_t)(i0 + r) * KPH + (u0 >> 1) + c * 8) = make_uint2(w0, w1);
  }
  if (t < 64) {
    const int cc = colp[0][t] + colp[1][t] + colp[2][t] + colp[3][t];
    if (i0 + t < NI && cc) atomicAdd(&Nv[i0 + t], cc);
    if (u0 + t < NU && rowc[t]) atomicAdd(&Nu[u0 + t], rowc[t]);
  }
}

// ---------------------------------------------------------------------------
// K2: P build (int8, x256 scale), vectorized (R13); blocks 1280..1343 do the
//  one-time f32->bf16 weight conversion grid-stride (64 blocks, NOT one).
// ---------------------------------------------------------------------------
__global__ __launch_bounds__(256) void k_pbuild(const float* __restrict__ msgW,
                                                const int* __restrict__ Nu,
                                                const int* __restrict__ Nv,
                                                int8_t* __restrict__ Pu,
                                                int8_t* __restrict__ Pv,
                                                const float* __restrict__ dW,
                                                const float* __restrict__ uW1,
                                                const float* __restrict__ vW1,
                                                const float* __restrict__ uW2,
                                                const float* __restrict__ vW2,
                                                __hip_bfloat16* __restrict__ dWb,
                                                __hip_bfloat16* __restrict__ W1b,
                                                __hip_bfloat16* __restrict__ W2b) {
  const int b = blockIdx.x;                 // 0..1279: P rows; 1280..1343: wcvt
  if (b >= 1280) {
    const int tid = (b - 1280) * 256 + threadIdx.x;
    const int stride = 64 * 256;
    for (int idx = tid; idx < 80 * 256; idx += stride) {
      const int oc = idx >> 8, k = idx & 255;
      dWb[idx] = __float2bfloat16(oc < 75 ? dW[oc * 256 + k] : 0.f);
    }
    for (int idx = tid; idx < 2 * 64 * 128; idx += stride) {
      const int s = idx >> 13, r = idx & 8191;
      W1b[idx] = __float2bfloat16(s ? vW1[r] : uW1[r]);
    }
    for (int idx = tid; idx < 2 * 80 * 64; idx += stride) {
      const int s = idx / 5120, r = idx % 5120;
      const int oc = r >> 6, k = r & 63;
      const float* W2 = s ? vW2 : uW2;
      W2b[idx] = __float2bfloat16(oc < 75 ? W2[oc * 64 + k] : 0.f);
    }
    return;
  }
  const float* src = msgW + (size_t)b * (NU + NI);
#pragma unroll
  for (int it = 0; it < 2; ++it) {
    const int base = (threadIdx.x + it * 256) * 8;     // 0..4088, 8-aligned
    uint32_t lou = 0, hiu = 0, lov = 0, hiv = 0;
    if (base < NU) {                                    // NU = 8*500
      const f32x4 v0 = *(const f32x4*)(src + base);
      const f32x4 v1 = *(const f32x4*)(src + base + 4);
      const f32x4 u0 = *(const f32x4*)(src + NU + base);
      const f32x4 u1 = *(const f32x4*)(src + NU + base + 4);
      const int4 cu0 = *(const int4*)(Nu + base);
      const int4 cu1 = *(const int4*)(Nu + base + 4);
      const int4 cv0 = *(const int4*)(Nv + base);
      const int4 cv1 = *(const int4*)(Nv + base + 4);
      float qv[8], qu[8];
      const int cus[8] = {cu0.x, cu0.y, cu0.z, cu0.w, cu1.x, cu1.y, cu1.z, cu1.w};
      const int cvs[8] = {cv0.x, cv0.y, cv0.z, cv0.w, cv1.x, cv1.y, cv1.z, cv1.w};
      const float vs[8] = {v0[0], v0[1], v0[2], v0[3], v1[0], v1[1], v1[2], v1[3]};
      const float us[8] = {u0[0], u0[1], u0[2], u0[3], u1[0], u1[1], u1[2], u1[3]};
#pragma unroll
      for (int j = 0; j < 8; ++j) {
        const float su = cus[j] > 0 ? rsqrtf((float)cus[j]) * 256.0f : 0.f;
        const float sv = cvs[j] > 0 ? rsqrtf((float)cvs[j]) * 256.0f : 0.f;
        qv[j] = fminf(fmaxf(vs[j] * su, -127.f), 127.f);
        qu[j] = fminf(fmaxf(us[j] * sv, -127.f), 127.f);
      }
      uint32_t bv[8], bu[8];
#pragma unroll
      for (int j = 0; j < 8; ++j) {
        bv[j] = (uint32_t)(uint8_t)(int8_t)__float2int_rn(qv[j]);
        bu[j] = (uint32_t)(uint8_t)(int8_t)__float2int_rn(qu[j]);
      }
      lov = bv[0] | (bv[2] << 8) | (bv[4] << 16) | (bv[6] << 24);
      hiv = bv[1] | (bv[3] << 8) | (bv[5] << 16) | (bv[7] << 24);
      lou = bu[0] | (bu[2] << 8) | (bu[4] << 16) | (bu[6] << 24);
      hiu = bu[1] | (bu[3] << 8) | (bu[5] << 16) | (bu[7] << 24);
    }
    *(uint2*)(Pv + (size_t)b * KP + base) = make_uint2(lov, hiv);
    *(uint2*)(Pu + (size_t)b * KP + base) = make_uint2(lou, hiu);
  }
}

// ---------------------------------------------------------------------------
// K3: one-hot i8 MFMA GEMM — 64-col waves, occupancy-4 geometry. (proven R17)
// ---------------------------------------------------------------------------
#define GLOAD_LDS(g, s) __builtin_amdgcn_global_load_lds( \
    (const __attribute__((address_space(1))) uint32_t*)(g), \
    (__attribute__((address_space(3))) uint32_t*)(s), 16, 0, 0)

static __device__ __forceinline__ uint32_t ohp(uint32_t sel, int r) {
  // one-hot i8: result byte = 0x01 iff input byte == r+1 (inputs 0..5)
  const uint32_t TL[5] = {0x00000100u, 0x00010000u, 0x01000000u, 0u, 0u};
  const uint32_t TH[5] = {0u, 0u, 0u, 0x00000001u, 0x00000100u};
  return __builtin_amdgcn_perm(TH[r], TL[r], sel);
}

__global__ __launch_bounds__(256, 4) void k_gemm(const uint8_t* __restrict__ Au,
                                                 const uint8_t* __restrict__ Av,
                                                 const int8_t* __restrict__ Pu,
                                                 const int8_t* __restrict__ Pv,
                                                 const int* __restrict__ Nu,
                                                 const int* __restrict__ Nv,
                                                 __hip_bfloat16* __restrict__ Hp) {
  __shared__ __attribute__((aligned(16))) char Bls[2][20480];

  const int bid = blockIdx.x;
  const int side = bid & 1;
  const int bn = (bid >> 1) & 3;                   // 0..3 (64-col slices)
  const int rest = bid >> 3;                       // 0..127
  const int ks = rest & 3;                         // 0..3
  const int bm = rest >> 2;                        // 0..31 (128-row tiles)
  const uint8_t* __restrict__ A8 = side ? Av : Au;
  const int8_t* __restrict__ P  = side ? Pv : Pu;
  const int* __restrict__ cnt = side ? Nv : Nu;
  const int kbeg = ks * 1024;
  const int nst = 16;                              // uniform steps of 64

  const int t = threadIdx.x;
  const int w = t >> 6, l = t & 63;
  const int l15 = l & 15, l4 = l >> 4;

  // staging: 20 gload_lds per block, 5 per wave (n = w*5+i). (proven maps)
  uint32_t soff[5], ldst[5];
  {
    const uint32_t jsrc = (uint32_t)((l & 3) ^ ((l >> 3) & 3));
#pragma unroll
    for (int i = 0; i < 5; ++i) {
      const int n = w * 5 + i;
      const int r = n >> 2, chunk = n & 3;
      const int colg = bn * 64 + chunk * 16 + (l >> 2);
      soff[i] = (uint32_t)(r * 256 + colg) * KP + jsrc * 16u;
      ldst[i] = (uint32_t)(n << 10);
    }
  }
#define STAGE(bi, kk) { _Pragma("unroll") \
  for (int i_ = 0; i_ < 5; ++i_) \
    GLOAD_LDS(P + soff[i_] + (uint32_t)(kk), &Bls[bi][0] + ldst[i_]); }

  // B read base: frag(r,c) at r*4096 + c*1024 + l15*64 + ((l4^((l15>>1)&3))<<4)
  const uint32_t rbase = (uint32_t)(l15 * 64) +
                         ((uint32_t)(l4 ^ ((l15 >> 1) & 3)) << 4);

  // A: packed byte offset per 16-row frag g (rows bm*128 + w*32 + g*16 + l15)
  uint32_t paoff[2];
#pragma unroll
  for (int g = 0; g < 2; ++g)
    paoff[g] = (uint32_t)(bm * 128 + w * 32 + g * 16 + l15) * KPH + l4 * 8;

  i32x4 acc[2][4] = {};
  uint2 aC[2], aN[2];

  STAGE(0, kbeg);
#pragma unroll
  for (int g = 0; g < 2; ++g)
    aC[g] = *(const uint2*)(A8 + paoff[g] + (kbeg >> 1));
  __syncthreads();

  for (int st = 0; st < nst; ++st) {
    const int kk = kbeg + st * 64;
    if (st + 1 < nst) {
      STAGE((st & 1) ^ 1, kk + 64);
#pragma unroll
      for (int g = 0; g < 2; ++g)
        aN[g] = *(const uint2*)(A8 + paoff[g] + ((kk + 64) >> 1));
    }
    // unpack nibbles -> 4 byte-dwords per frag (k-order matches P permutation)
    uint32_t ud[2][4];
#pragma unroll
    for (int g = 0; g < 2; ++g) {
      ud[g][0] = aC[g].x & 0x0F0F0F0Fu;
      ud[g][1] = (aC[g].x >> 4) & 0x0F0F0F0Fu;
      ud[g][2] = aC[g].y & 0x0F0F0F0Fu;
      ud[g][3] = (aC[g].y >> 4) & 0x0F0F0F0Fu;
    }
    const char* lb = &Bls[st & 1][0];
#pragma unroll
    for (int r = 0; r < 5; ++r) {
      const uint4 B0 = *(const uint4*)(lb + r * 4096 + rbase);
      const uint4 B1 = *(const uint4*)(lb + r * 4096 + rbase + 1024);
      const uint4 B2 = *(const uint4*)(lb + r * 4096 + rbase + 2048);
      const uint4 B3 = *(const uint4*)(lb + r * 4096 + rbase + 3072);
#pragma unroll
      for (int g = 0; g < 2; ++g) {
        uint4 af;
        af.x = ohp(ud[g][0], r); af.y = ohp(ud[g][1], r);
        af.z = ohp(ud[g][2], r); af.w = ohp(ud[g][3], r);
        const i32x4 a4 = __builtin_bit_cast(i32x4, af);
        acc[g][0] = __builtin_amdgcn_mfma_i32_16x16x64_i8(
            a4, __builtin_bit_cast(i32x4, B0), acc[g][0], 0, 0, 0);
        acc[g][1] = __builtin_amdgcn_mfma_i32_16x16x64_i8(
            a4, __builtin_bit_cast(i32x4, B1), acc[g][1], 0, 0, 0);
        acc[g][2] = __builtin_amdgcn_mfma_i32_16x16x64_i8(
            a4, __builtin_bit_cast(i32x4, B2), acc[g][2], 0, 0, 0);
        acc[g][3] = __builtin_amdgcn_mfma_i32_16x16x64_i8(
            a4, __builtin_bit_cast(i32x4, B3), acc[g][3], 0, 0, 0);
      }
    }
#pragma unroll
    for (int g = 0; g < 2; ++g) aC[g] = aN[g];
    __syncthreads();
  }

  // epilogue: scale by rsqrt(cnt)/256, store bf16 partial (relu deferred)
  __hip_bfloat16* hp = Hp + (size_t)(ks * 2 + side) * HP_STRIDE;
#pragma unroll
  for (int g = 0; g < 2; ++g) {
    const int rowb = bm * 128 + w * 32 + g * 16 + l4 * 4;
#pragma unroll
    for (int c = 0; c < 4; ++c) {
      const int ocol = bn * 64 + c * 16 + l15;
#pragma unroll
      for (int q = 0; q < 4; ++q) {
        const int orow = rowb + q;
        if (orow < 4000) {
          const int cv = cnt[orow];
          const float s = cv > 0 ? rsqrtf((float)cv) * (1.0f / 256.0f) : 0.f;
          hp[(size_t)orow * 256 + ocol] = __float2bfloat16((float)acc[g][c][q] * s);
        }
      }
    }
  }
#undef STAGE
}

// ---------------------------------------------------------------------------
// K4: fused stage 2 — 128 thr (2 waves), 16 rows/block, kh = K-split.
//  Hsum = relu(sum of 4 partials per side at offsets 0,2,4,6 x HP_STRIDE).
//  grid 500 = 2 sides x 250 -> ~2 blocks/CU (was 250 -> 1/CU with idle CUs).
// ---------------------------------------------------------------------------
__global__ __launch_bounds__(128) void k_out(const __hip_bfloat16* __restrict__ Hp,
                                             const float* __restrict__ usf,
                                             const float* __restrict__ vsf,
                                             const __hip_bfloat16* __restrict__ dWb,
                                             const __hip_bfloat16* __restrict__ W1b,
                                             const float* __restrict__ ub1,
                                             const float* __restrict__ vb1,
                                             const __hip_bfloat16* __restrict__ W2b,
                                             float* __restrict__ out) {
  const int bid = blockIdx.x;               // 0..499
  const int side = bid / 250, rb = bid % 250;
  const int t = threadIdx.x, kh = t >> 6, l = t & 63;
  const int l15 = l & 15, l4 = l >> 4;
  const float* __restrict__ sf = side ? vsf : usf;
  const float* __restrict__ b1 = side ? vb1 : ub1;
  const __hip_bfloat16* __restrict__ W1 = W1b + side * (64 * 128);
  const __hip_bfloat16* __restrict__ W2 = W2b + side * (80 * 64);
  const __hip_bfloat16* __restrict__ hp = Hp + (size_t)side * HP_STRIDE;
  const int r0 = rb * 16;
  const int myrow = r0 + l15;

  __shared__ __hip_bfloat16 lf[16][72];
  __shared__ float ps[80][20];

  f32x4 oA[5] = {};
  const __hip_bfloat16* hbase = hp + (size_t)myrow * 256 + 8 * l4;

#define PHASE_B_HALF(kb) { \
  _Pragma("unroll") \
  for (int i_ = 0; i_ < 4; ++i_) { \
    const int kk_ = (kb) + i_ * 32; \
    const bf16x8 q0 = *(const bf16x8*)(hbase + kk_); \
    const bf16x8 q1 = *(const bf16x8*)(hbase + 2 * HP_STRIDE + kk_); \
    const bf16x8 q2 = *(const bf16x8*)(hbase + 4 * HP_STRIDE + kk_); \
    const bf16x8 q3 = *(const bf16x8*)(hbase + 6 * HP_STRIDE + kk_); \
    bf16x8 af; \
    _Pragma("unroll") \
    for (int j_ = 0; j_ < 8; ++j_) { \
      float hv = b2f(q0[j_]) + b2f(q1[j_]) + b2f(q2[j_]) + b2f(q3[j_]); \
      af[j_] = f2b(hv > 0.f ? hv : 0.f); \
    } \
    _Pragma("unroll") \
    for (int c_ = 0; c_ < 5; ++c_) { \
      const bf16x8 bf = *(const bf16x8*)(dWb + (c_ * 16 + l15) * 256 + kk_ + 8 * l4); \
      oA[c_] = __builtin_amdgcn_mfma_f32_16x16x32_bf16(af, bf, oA[c_], 0, 0, 0); \
    } \
  } }

  if (kh == 0) {
    // Phase A: F = relu(sf @ W1^T + b1)
    f32x4 fA[4] = {};
#pragma unroll
    for (int kk = 0; kk < 128; kk += 32) {
      const float* psf = sf + (size_t)myrow * 128 + kk + 8 * l4;
      const bf16x8 af = cvt8(*(const f32x4*)psf, *(const f32x4*)(psf + 4));
#pragma unroll
      for (int c = 0; c < 4; ++c) {
        const bf16x8 bf = *(const bf16x8*)(W1 + (c * 16 + l15) * 128 + kk + 8 * l4);
        fA[c] = __builtin_amdgcn_mfma_f32_16x16x32_bf16(af, bf, fA[c], 0, 0, 0);
      }
    }
#pragma unroll
    for (int c = 0; c < 4; ++c) {
      const float bv = b1[c * 16 + l15];
#pragma unroll
      for (int reg = 0; reg < 4; ++reg) {
        float v = fA[c][reg] + bv;
        lf[l4 * 4 + reg][c * 16 + l15] = __float2bfloat16(v > 0.f ? v : 0.f);
      }
    }
  } else {
    PHASE_B_HALF(128)
  }
  __syncthreads();
  if (kh == 0) {
    PHASE_B_HALF(0)
  } else {
    // W2 part: out += F @ W2^T (K=64), F from LDS
#pragma unroll
    for (int kk = 0; kk < 64; kk += 32) {
      const bf16x8 af = *(const bf16x8*)(&lf[l15][kk + 8 * l4]);
#pragma unroll
      for (int c = 0; c < 5; ++c) {
        const bf16x8 bf = *(const bf16x8*)(W2 + (c * 16 + l15) * 64 + kk + 8 * l4);
        oA[c] = __builtin_amdgcn_mfma_f32_16x16x32_bf16(af, bf, oA[c], 0, 0, 0);
      }
    }
    // store partials
#pragma unroll
    for (int c = 0; c < 5; ++c)
      *(f32x4*)&ps[c * 16 + l15][l4 * 4] = oA[c];
  }
  __syncthreads();
  if (kh == 0) {
    float* po = out + (size_t)side * (4000 * 75);
#pragma unroll
    for (int c = 0; c < 5; ++c) {
      const int oc = c * 16 + l15;
      if (oc < 75) {
        const f32x4 pv = *(const f32x4*)&ps[oc][l4 * 4];
#pragma unroll
        for (int reg = 0; reg < 4; ++reg) {
          const int orow = r0 + l4 * 4 + reg;
          const float v = oA[c][reg] + pv[reg];
          po[(size_t)orow * 75 + oc] = v > 0.f ? v : 0.f;
        }
      }
    }
  }
#undef PHASE_B_HALF
}

// ---------------------------------------------------------------------------
extern "C" void kernel_launch(void* const* d_in, const int* in_sizes, int n_in,
                              void* d_out, int out_size, void* d_ws, size_t ws_size,
                              hipStream_t stream) {
  const int* adj = (const int*)d_in[0];
  const float* usf = (const float*)d_in[1];
  const float* vsf = (const float*)d_in[2];
  const float* msgW = (const float*)d_in[3];
  const float* dW = (const float*)d_in[4];
  const float* uW1 = (const float*)d_in[5];
  const float* ub1 = (const float*)d_in[6];
  const float* uW2 = (const float*)d_in[7];
  const float* vW1 = (const float*)d_in[8];
  const float* vb1 = (const float*)d_in[9];
  const float* vW2 = (const float*)d_in[10];
  float* out = (float*)d_out;

  char* w = (char*)d_ws;
  const size_t A_BYTES = (size_t)4096 * KPH;            // 8,388,608 per side
  const size_t P_BYTES = (size_t)RR * MM * KP;          // 5,242,880 (int8)
  const size_t HP_BYTES = (size_t)8 * HP_STRIDE * 2;    // 16,384,000 (bf16)
  int* Nu = (int*)w;
  int* Nv = (int*)(w + 16384);
  uint8_t* Au = (uint8_t*)(w + 32768);
  uint8_t* Av = Au + A_BYTES;
  int8_t* Pu = (int8_t*)(w + 32768 + 2 * A_BYTES);
  int8_t* Pv = Pu + P_BYTES;
  __hip_bfloat16* Hp = (__hip_bfloat16*)(w + 32768 + 2 * A_BYTES + 2 * P_BYTES);
  char* wb = (char*)(Hp) + HP_BYTES;
  __hip_bfloat16* dWb = (__hip_bfloat16*)wb;                       // 40960 B
  __hip_bfloat16* W1b = (__hip_bfloat16*)(wb + 40960);             // 32768 B
  __hip_bfloat16* W2b = (__hip_bfloat16*)(wb + 40960 + 32768);     // 20480 B
  const size_t need = 32768 + 2 * A_BYTES + 2 * P_BYTES + HP_BYTES + 94208;
  if (ws_size < need) return;                            // ~43.8 MB

  hipMemsetAsync(w, 0, 32768, stream);
  k_trans<<<dim3(64, 64), 256, 0, stream>>>(adj, Au, Av, Nu, Nv);
  k_pbuild<<<1344, 256, 0, stream>>>(msgW, Nu, Nv, Pu, Pv, dW, uW1, vW1, uW2,
                                     vW2, dWb, W1b, W2b);
  k_gemm<<<1024, 256, 0, stream>>>(Au, Av, Pu, Pv, Nu, Nv, Hp);
  k_out<<<500, 128, 0, stream>>>(Hp, usf, vsf, dWb, W1b, ub1, vb1, W2b, out);
}